// Round 1
// baseline (953.861 us; speedup 1.0000x reference)
//
#include <hip/hip_runtime.h>
#include <math.h>

#define IN_DIM 128
#define HEADS 4
#define CH 128
#define HC 512   // HEADS*CH
#define GRAPHS 128
#define OUT_DIM 8

// ---------------- CSR build ----------------
__global__ void k_count(const int* __restrict__ ei, int* __restrict__ counts, int E, int N) {
  int i = blockIdx.x * blockDim.x + threadIdx.x;
  int total = E + N;
  if (i >= total) return;
  int dst = (i < E) ? ei[E + i] : (i - E);
  atomicAdd(&counts[dst], 1);
}

__global__ __launch_bounds__(1024) void k_scan(const int* __restrict__ counts,
                                               int* __restrict__ indptr,
                                               int* __restrict__ cursor, int N) {
  __shared__ int part[1024];
  int t = threadIdx.x;
  int chunk = (N + 1023) >> 10;
  int lo = t * chunk;
  int hi = min(lo + chunk, N);
  int s = 0;
  for (int i = lo; i < hi; i++) s += counts[i];
  part[t] = s;
  __syncthreads();
  for (int off = 1; off < 1024; off <<= 1) {
    int v = part[t];
    int u = (t >= off) ? part[t - off] : 0;
    __syncthreads();
    part[t] = v + u;
    __syncthreads();
  }
  int run = (t == 0) ? 0 : part[t - 1];
  for (int i = lo; i < hi; i++) { indptr[i] = run; cursor[i] = run; run += counts[i]; }
  if (hi == N && lo <= N) indptr[N] = run;
}

__global__ void k_scatter(const int* __restrict__ ei, int* __restrict__ cursor,
                          int* __restrict__ srcs, int E, int N) {
  int i = blockIdx.x * blockDim.x + threadIdx.x;
  int total = E + N;
  if (i >= total) return;
  int src, dst;
  if (i < E) { src = ei[i]; dst = ei[E + i]; } else { src = i - E; dst = i - E; }
  int pos = atomicAdd(&cursor[dst], 1);
  srcs[pos] = src;
}

// ---------------- fp32 tiled GEMM: C[M,N] = A[M,K] @ B[K,N] ----------------
// BM=BN=64, BK=32, 256 threads, 4x4 per thread. N,K multiples required (true here).
__global__ __launch_bounds__(256) void k_gemm(const float* __restrict__ A,
                                              const float* __restrict__ B,
                                              float* __restrict__ C,
                                              int M, int N, int K) {
  __shared__ float As[64][36];
  __shared__ float Bs[32][64];
  int t = threadIdx.x;
  int tx = t & 15, ty = t >> 4;
  int r0 = blockIdx.x * 64;
  int c0 = blockIdx.y * 64;
  float acc[4][4] = {};
  for (int kt = 0; kt < K; kt += 32) {
    #pragma unroll
    for (int q = t; q < 512; q += 256) {
      int row = q >> 3, c4 = q & 7;
      int gr = r0 + row;
      float4 v = make_float4(0.f, 0.f, 0.f, 0.f);
      if (gr < M) v = *(const float4*)&A[(size_t)gr * K + kt + c4 * 4];
      As[row][c4 * 4 + 0] = v.x; As[row][c4 * 4 + 1] = v.y;
      As[row][c4 * 4 + 2] = v.z; As[row][c4 * 4 + 3] = v.w;
    }
    #pragma unroll
    for (int q = t; q < 512; q += 256) {
      int kr = q >> 4, c4 = q & 15;
      float4 v = *(const float4*)&B[(size_t)(kt + kr) * N + c0 + c4 * 4];
      *(float4*)&Bs[kr][c4 * 4] = v;
    }
    __syncthreads();
    #pragma unroll
    for (int kk = 0; kk < 32; kk++) {
      float a[4];
      #pragma unroll
      for (int i = 0; i < 4; i++) a[i] = As[ty * 4 + i][kk];
      float4 b = *(float4*)&Bs[kk][tx * 4];
      #pragma unroll
      for (int i = 0; i < 4; i++) {
        acc[i][0] += a[i] * b.x; acc[i][1] += a[i] * b.y;
        acc[i][2] += a[i] * b.z; acc[i][3] += a[i] * b.w;
      }
    }
    __syncthreads();
  }
  #pragma unroll
  for (int i = 0; i < 4; i++) {
    int gr = r0 + ty * 4 + i;
    if (gr < M) {
      float4 v = make_float4(acc[i][0], acc[i][1], acc[i][2], acc[i][3]);
      *(float4*)&C[(size_t)gr * N + c0 + tx * 4] = v;
    }
  }
}

// ---------------- attention projections ----------------
__global__ void k_att_h4(const float* __restrict__ hm, const float* __restrict__ att_s,
                         const float* __restrict__ att_d, float* __restrict__ s_out,
                         float* __restrict__ d_out, int N) {
  int wid = blockIdx.x * (blockDim.x >> 6) + (threadIdx.x >> 6);
  int lane = threadIdx.x & 63;
  if (wid >= N) return;
  const float* row = hm + (size_t)wid * HC;
  float ps[HEADS], pd[HEADS];
  #pragma unroll
  for (int hh = 0; hh < HEADS; hh++) {
    float x0 = row[hh * CH + lane], x1 = row[hh * CH + 64 + lane];
    ps[hh] = x0 * att_s[hh * CH + lane] + x1 * att_s[hh * CH + 64 + lane];
    pd[hh] = x0 * att_d[hh * CH + lane] + x1 * att_d[hh * CH + 64 + lane];
  }
  #pragma unroll
  for (int off = 32; off; off >>= 1) {
    #pragma unroll
    for (int hh = 0; hh < HEADS; hh++) {
      ps[hh] += __shfl_xor(ps[hh], off);
      pd[hh] += __shfl_xor(pd[hh], off);
    }
  }
  if (lane == 0) {
    #pragma unroll
    for (int hh = 0; hh < HEADS; hh++) {
      s_out[wid * HEADS + hh] = ps[hh];
      d_out[wid * HEADS + hh] = pd[hh];
    }
  }
}

__global__ void k_att_h1(const float* __restrict__ hm, const float* __restrict__ att_s,
                         const float* __restrict__ att_d, float* __restrict__ s_out,
                         float* __restrict__ d_out, int N) {
  int wid = blockIdx.x * (blockDim.x >> 6) + (threadIdx.x >> 6);
  int lane = threadIdx.x & 63;
  if (wid >= N) return;
  const float* row = hm + (size_t)wid * CH;
  float x0 = row[lane], x1 = row[64 + lane];
  float ps = x0 * att_s[lane] + x1 * att_s[64 + lane];
  float pd = x0 * att_d[lane] + x1 * att_d[64 + lane];
  #pragma unroll
  for (int off = 32; off; off >>= 1) {
    ps += __shfl_xor(ps, off);
    pd += __shfl_xor(pd, off);
  }
  if (lane == 0) { s_out[wid] = ps; d_out[wid] = pd; }
}

// ---------------- conv1: fused segment-softmax + aggregate + bias + LN + ReLU ----------------
__global__ __launch_bounds__(256) void k_agg1(
    const float* __restrict__ hm, const int* __restrict__ indptr,
    const int* __restrict__ srcs, const float* __restrict__ as1,
    const float* __restrict__ ad1, const float* __restrict__ bias,
    const float* __restrict__ gam, const float* __restrict__ bet,
    float* __restrict__ out, int N) {
  int n = blockIdx.x;
  if (n >= N) return;
  int t = threadIdx.x;
  int lane = t & 63, wid = t >> 6;
  int beg = indptr[n], end = indptr[n + 1];
  __shared__ float s_wmax[4][HEADS];
  __shared__ float s_max[HEADS];
  __shared__ float s_den[HEADS];
  __shared__ int s_src[64];
  __shared__ float s_w[64][HEADS];
  __shared__ float2 s_red[256];
  float ad[HEADS];
  #pragma unroll
  for (int hh = 0; hh < HEADS; hh++) ad[hh] = ad1[n * HEADS + hh];
  // phase 1: per-head max of leaky_relu scores
  float mx[HEADS] = {-1e30f, -1e30f, -1e30f, -1e30f};
  for (int e = beg + t; e < end; e += 256) {
    int s = srcs[e];
    #pragma unroll
    for (int hh = 0; hh < HEADS; hh++) {
      float v = as1[s * HEADS + hh] + ad[hh];
      v = v > 0.f ? v : 0.2f * v;
      mx[hh] = fmaxf(mx[hh], v);
    }
  }
  #pragma unroll
  for (int off = 32; off; off >>= 1)
    #pragma unroll
    for (int hh = 0; hh < HEADS; hh++)
      mx[hh] = fmaxf(mx[hh], __shfl_xor(mx[hh], off));
  if (lane == 0)
    #pragma unroll
    for (int hh = 0; hh < HEADS; hh++) s_wmax[wid][hh] = mx[hh];
  __syncthreads();
  if (t < HEADS)
    s_max[t] = fmaxf(fmaxf(s_wmax[0][t], s_wmax[1][t]), fmaxf(s_wmax[2][t], s_wmax[3][t]));
  __syncthreads();
  // phase 2: exp weights + weighted aggregate, chunked by 64 edges
  int c0 = t, c1 = t + 256;
  int hA = t >> 7, hB = hA + 2;
  int myh = t & 3;
  float mymax = s_max[myh];
  float dsum = 0.f, acc0 = 0.f, acc1 = 0.f;
  for (int base = beg; base < end; base += 64) {
    int cnt = min(64, end - base);
    if (t < cnt * 4) {
      int j = t >> 2, hh = t & 3;
      int s = srcs[base + j];
      if (hh == 0) s_src[j] = s;
      float v = as1[s * HEADS + hh] + ad[hh];
      v = v > 0.f ? v : 0.2f * v;
      float w = __expf(v - mymax);
      s_w[j][hh] = w;
      dsum += w;
    }
    __syncthreads();
    for (int j = 0; j < cnt; j++) {
      int s = s_src[j];
      const float* hr = hm + (size_t)s * HC;
      acc0 += hr[c0] * s_w[j][hA];
      acc1 += hr[c1] * s_w[j][hB];
    }
    __syncthreads();
  }
  // denominators per head
  s_red[t].x = dsum;
  __syncthreads();
  if (t < HEADS) {
    float d = 0.f;
    for (int q = t; q < 256; q += 4) d += s_red[q].x;
    s_den[t] = d + 1e-16f;
  }
  __syncthreads();
  float v0 = acc0 / s_den[hA] + bias[c0];
  float v1 = acc1 / s_den[hB] + bias[c1];
  __syncthreads();
  // LayerNorm over 512 channels
  s_red[t] = make_float2(v0 + v1, v0 * v0 + v1 * v1);
  __syncthreads();
  for (int off = 128; off; off >>= 1) {
    if (t < off) {
      s_red[t].x += s_red[t + off].x;
      s_red[t].y += s_red[t + off].y;
    }
    __syncthreads();
  }
  float mean = s_red[0].x * (1.f / 512.f);
  float var = s_red[0].y * (1.f / 512.f) - mean * mean;
  float rs = rsqrtf(var + 1e-5f);
  float y0 = (v0 - mean) * rs * gam[c0] + bet[c0];
  float y1 = (v1 - mean) * rs * gam[c1] + bet[c1];
  out[(size_t)n * HC + c0] = fmaxf(y0, 0.f);
  out[(size_t)n * HC + c1] = fmaxf(y1, 0.f);
}

// ---------------- conv2: 1 head, 128 channels ----------------
__global__ __launch_bounds__(128) void k_agg2(
    const float* __restrict__ hm, const int* __restrict__ indptr,
    const int* __restrict__ srcs, const float* __restrict__ as2,
    const float* __restrict__ ad2, const float* __restrict__ bias,
    const float* __restrict__ gam, const float* __restrict__ bet,
    float* __restrict__ out, int N) {
  int n = blockIdx.x;
  if (n >= N) return;
  int t = threadIdx.x;
  int lane = t & 63, wid = t >> 6;
  int beg = indptr[n], end = indptr[n + 1];
  __shared__ float s_wmax[2];
  __shared__ float s_scal[2];   // [0]=max, [1]=denom
  __shared__ int s_src[128];
  __shared__ float s_w[128];
  __shared__ float2 s_red[128];
  float adv = ad2[n];
  float mx = -1e30f;
  for (int e = beg + t; e < end; e += 128) {
    float v = as2[srcs[e]] + adv;
    v = v > 0.f ? v : 0.2f * v;
    mx = fmaxf(mx, v);
  }
  #pragma unroll
  for (int off = 32; off; off >>= 1) mx = fmaxf(mx, __shfl_xor(mx, off));
  if (lane == 0) s_wmax[wid] = mx;
  __syncthreads();
  if (t == 0) s_scal[0] = fmaxf(s_wmax[0], s_wmax[1]);
  __syncthreads();
  float m = s_scal[0];
  float dsum = 0.f, acc = 0.f;
  for (int base = beg; base < end; base += 128) {
    int cnt = min(128, end - base);
    if (t < cnt) {
      int s = srcs[base + t];
      s_src[t] = s;
      float v = as2[s] + adv;
      v = v > 0.f ? v : 0.2f * v;
      float w = __expf(v - m);
      s_w[t] = w;
      dsum += w;
    }
    __syncthreads();
    for (int j = 0; j < cnt; j++)
      acc += hm[(size_t)s_src[j] * CH + t] * s_w[j];
    __syncthreads();
  }
  s_red[t].x = dsum;
  __syncthreads();
  for (int off = 64; off; off >>= 1) {
    if (t < off) s_red[t].x += s_red[t + off].x;
    __syncthreads();
  }
  float den = s_red[0].x + 1e-16f;
  __syncthreads();
  float v = acc / den + bias[t];
  s_red[t] = make_float2(v, v * v);
  __syncthreads();
  for (int off = 64; off; off >>= 1) {
    if (t < off) {
      s_red[t].x += s_red[t + off].x;
      s_red[t].y += s_red[t + off].y;
    }
    __syncthreads();
  }
  float mean = s_red[0].x * (1.f / 128.f);
  float var = s_red[0].y * (1.f / 128.f) - mean * mean;
  float rs = rsqrtf(var + 1e-5f);
  float y = (v - mean) * rs * gam[t] + bet[t];
  out[(size_t)n * CH + t] = fmaxf(y, 0.f);
}

// ---------------- global mean pool ----------------
__global__ void k_pool(const float* __restrict__ h2, const int* __restrict__ batch,
                       float* __restrict__ psum, int N) {
  int i = blockIdx.x * blockDim.x + threadIdx.x;
  if (i >= N * CH) return;
  int n = i >> 7;
  atomicAdd(&psum[(size_t)batch[n] * CH + (i & 127)], h2[i]);
}

__global__ void k_cnt(const int* __restrict__ batch, int* __restrict__ pcnt, int N) {
  int i = blockIdx.x * blockDim.x + threadIdx.x;
  if (i < N) atomicAdd(&pcnt[batch[i]], 1);
}

// ---------------- MLP head ----------------
__global__ __launch_bounds__(128) void k_head(const float* __restrict__ psum,
    const int* __restrict__ pcnt, const float* __restrict__ rW1, const float* __restrict__ rb1,
    const float* __restrict__ rg, const float* __restrict__ rbe,
    const float* __restrict__ rW2, const float* __restrict__ rb2,
    float* __restrict__ outp) {
  int g = blockIdx.x, t = threadIdx.x;
  __shared__ float pl[128];
  __shared__ float yv[32];
  __shared__ float rv[32];
  __shared__ float mv[2];
  float cnt = fmaxf((float)pcnt[g], 1.f);
  pl[t] = psum[g * 128 + t] / cnt;
  __syncthreads();
  if (t < 32) {
    float s = rb1[t];
    for (int c = 0; c < 128; c++) s += pl[c] * rW1[c * 32 + t];
    yv[t] = s;
  }
  __syncthreads();
  if (t == 0) {
    float s = 0.f, sq = 0.f;
    for (int j = 0; j < 32; j++) { s += yv[j]; sq += yv[j] * yv[j]; }
    float mean = s / 32.f;
    float var = sq / 32.f - mean * mean;
    mv[0] = mean; mv[1] = rsqrtf(var + 1e-5f);
  }
  __syncthreads();
  if (t < 32) {
    float y = (yv[t] - mv[0]) * mv[1] * rg[t] + rbe[t];
    rv[t] = fmaxf(y, 0.f);
  }
  __syncthreads();
  if (t < OUT_DIM) {
    float s = rb2[t];
    for (int j = 0; j < 32; j++) s += rv[j] * rW2[j * 8 + t];
    outp[g * 8 + t] = s;
  }
}

extern "C" void kernel_launch(void* const* d_in, const int* in_sizes, int n_in,
                              void* d_out, int out_size, void* d_ws, size_t ws_size,
                              hipStream_t stream) {
  const float* x    = (const float*)d_in[0];
  const int*   ei   = (const int*)d_in[1];
  const int*   batch= (const int*)d_in[3];
  const float* W1   = (const float*)d_in[4];
  const float* as1w = (const float*)d_in[5];
  const float* ad1w = (const float*)d_in[6];
  const float* b1   = (const float*)d_in[7];
  const float* g1   = (const float*)d_in[8];
  const float* be1  = (const float*)d_in[9];
  const float* W2   = (const float*)d_in[10];
  const float* as2w = (const float*)d_in[11];
  const float* ad2w = (const float*)d_in[12];
  const float* b2   = (const float*)d_in[13];
  const float* g2   = (const float*)d_in[14];
  const float* be2  = (const float*)d_in[15];
  const float* rW1  = (const float*)d_in[16];
  const float* rb1  = (const float*)d_in[17];
  const float* rg   = (const float*)d_in[18];
  const float* rbe  = (const float*)d_in[19];
  const float* rW2  = (const float*)d_in[20];
  const float* rb2  = (const float*)d_in[21];

  int N = in_sizes[0] / IN_DIM;
  int E = in_sizes[1] / 2;
  int ET = E + N;

  float* ws   = (float*)d_ws;
  float* h    = ws;                          // N*512 (reused for conv2: raw2 + h2)
  float* h1   = h + (size_t)N * HC;          // N*512
  float* sa1  = h1 + (size_t)N * HC;         // N*4
  float* da1  = sa1 + (size_t)N * 4;         // N*4
  float* sa2  = da1 + (size_t)N * 4;         // N
  float* da2  = sa2 + N;                     // N
  float* psum = da2 + N;                     // 128*128
  int* pcnt   = (int*)(psum + GRAPHS * CH);  // 128
  int* counts = pcnt + GRAPHS;               // N
  int* indptr = counts + N;                  // N+1
  int* cursor = indptr + (N + 1);            // N
  int* srcs   = cursor + N;                  // ET
  float* raw2 = h;                           // N*128
  float* h2   = h + (size_t)N * CH;          // N*128

  hipMemsetAsync(counts, 0, (size_t)N * sizeof(int), stream);
  hipMemsetAsync(psum, 0, (size_t)GRAPHS * CH * sizeof(float), stream);
  hipMemsetAsync(pcnt, 0, (size_t)GRAPHS * sizeof(int), stream);

  int eb = (ET + 255) / 256;
  k_count<<<eb, 256, 0, stream>>>(ei, counts, E, N);
  k_scan<<<1, 1024, 0, stream>>>(counts, indptr, cursor, N);
  k_scatter<<<eb, 256, 0, stream>>>(ei, cursor, srcs, E, N);

  dim3 grid1((N + 63) / 64, HC / 64);
  k_gemm<<<grid1, 256, 0, stream>>>(x, W1, h, N, HC, IN_DIM);
  k_att_h4<<<(N + 3) / 4, 256, 0, stream>>>(h, as1w, ad1w, sa1, da1, N);
  k_agg1<<<N, 256, 0, stream>>>(h, indptr, srcs, sa1, da1, b1, g1, be1, h1, N);

  dim3 grid2((N + 63) / 64, CH / 64);
  k_gemm<<<grid2, 256, 0, stream>>>(h1, W2, raw2, N, CH, HC);
  k_att_h1<<<(N + 3) / 4, 256, 0, stream>>>(raw2, as2w, ad2w, sa2, da2, N);
  k_agg2<<<N, 128, 0, stream>>>(raw2, indptr, srcs, sa2, da2, b2, g2, be2, h2, N);

  k_pool<<<(N * CH + 255) / 256, 256, 0, stream>>>(h2, batch, psum, N);
  k_cnt<<<(N + 255) / 256, 256, 0, stream>>>(batch, pcnt, N);
  k_head<<<GRAPHS, 128, 0, stream>>>(psum, pcnt, rW1, rb1, rg, rbe, rW2, rb2, (float*)d_out);
}

// Round 2
// 763.533 us; speedup vs baseline: 1.2493x; 1.2493x over previous
//
#include <hip/hip_runtime.h>
#include <math.h>

#define HEADS 4
#define CH 128
#define HC 512
#define GRAPHS 128
#define OUT_DIM 8

typedef unsigned short u16;
typedef unsigned int u32;
typedef short short8 __attribute__((ext_vector_type(8)));
typedef float f32x4 __attribute__((ext_vector_type(4)));

__device__ inline u16 f2b(float f) {
  u32 u = __float_as_uint(f);
  u32 r = u + 0x7FFFu + ((u >> 16) & 1u);
  return (u16)(r >> 16);
}
__device__ inline float b2f(u16 u) { return __uint_as_float((u32)u << 16); }

// ---------------- CSR build ----------------
__global__ void k_count(const int* __restrict__ ei, int* __restrict__ counts, int E, int N) {
  int i = blockIdx.x * blockDim.x + threadIdx.x;
  int total = E + N;
  if (i >= total) return;
  int dst = (i < E) ? ei[E + i] : (i - E);
  atomicAdd(&counts[dst], 1);
}

__global__ __launch_bounds__(1024) void k_scan(const int* __restrict__ counts,
                                               int* __restrict__ indptr,
                                               int* __restrict__ cursor, int N) {
  __shared__ int part[1024];
  int t = threadIdx.x;
  int chunk = (N + 1023) >> 10;
  int lo = t * chunk;
  int hi = min(lo + chunk, N);
  int s = 0;
  for (int i = lo; i < hi; i++) s += counts[i];
  part[t] = s;
  __syncthreads();
  for (int off = 1; off < 1024; off <<= 1) {
    int v = part[t];
    int u = (t >= off) ? part[t - off] : 0;
    __syncthreads();
    part[t] = v + u;
    __syncthreads();
  }
  int run = (t == 0) ? 0 : part[t - 1];
  for (int i = lo; i < hi; i++) { indptr[i] = run; cursor[i] = run; run += counts[i]; }
  if (hi == N && lo <= N) indptr[N] = run;
}

__global__ void k_scatter(const int* __restrict__ ei, int* __restrict__ cursor,
                          int* __restrict__ srcs, int E, int N) {
  int i = blockIdx.x * blockDim.x + threadIdx.x;
  int total = E + N;
  if (i >= total) return;
  int src, dst;
  if (i < E) { src = ei[i]; dst = ei[E + i]; } else { src = i - E; dst = i - E; }
  int pos = atomicAdd(&cursor[dst], 1);
  srcs[pos] = src;
}

// ---------------- fp32 -> bf16 converters ----------------
__global__ void k_f2b(const float* __restrict__ in, u32* __restrict__ out, int n2) {
  int i = blockIdx.x * blockDim.x + threadIdx.x;
  if (i >= n2) return;
  float2 v = ((const float2*)in)[i];
  out[i] = (u32)f2b(v.x) | ((u32)f2b(v.y) << 16);
}

// W [K][Nc] fp32 -> Wt [Nc][K] bf16 (transposed)
__global__ void k_wt(const float* __restrict__ W, u16* __restrict__ Wt, int K, int Nc) {
  int i = blockIdx.x * blockDim.x + threadIdx.x;
  if (i >= K * Nc) return;
  int n = i / K, k = i - n * K;
  Wt[i] = f2b(W[(size_t)k * Nc + n]);
}

// ---------------- bf16 MFMA GEMM: C[M][Nc] = A[M][K] * Bt[Nc][K]^T ----------------
// 128x128 tile, BK=64, 4 waves (each 64x64 quadrant), global_load_lds staging
// with pre-swizzled source addresses; XOR-swizzled ds_read_b128 fragment loads.
__global__ __launch_bounds__(256) void k_gemm_bf16(
    const u16* __restrict__ A, const u16* __restrict__ Bt,
    u16* __restrict__ C, int M, int Nc, int K) {
  __shared__ u16 As[128 * 64];
  __shared__ u16 Bs[128 * 64];
  int t = threadIdx.x;
  int lane = t & 63, wid = t >> 6;
  int wr = wid >> 1, wc = wid & 1;
  int r0 = blockIdx.x * 128, c0 = blockIdx.y * 128;
  int lr = lane & 15, lk = lane >> 4;
  f32x4 acc[4][4] = {};

  for (int kt = 0; kt < K; kt += 64) {
    #pragma unroll
    for (int it = 0; it < 4; it++) {
      int q = wid * 4096 + it * 1024 + lane * 16;   // linear byte pos in tile
      int row = q >> 7;
      int soff = ((q >> 4) & 7) ^ (row & 7);        // pre-swizzled source chunk
      {
        int gr = r0 + row; if (gr >= M) gr = M - 1;
        const u16* gp = A + (size_t)gr * K + kt + soff * 8;
        __builtin_amdgcn_global_load_lds(
            (const __attribute__((address_space(1))) void*)gp,
            (__attribute__((address_space(3))) void*)((char*)As + wid * 4096 + it * 1024),
            16, 0, 0);
      }
      {
        int gn = c0 + row;   // Nc is a multiple of 128
        const u16* gp = Bt + (size_t)gn * K + kt + soff * 8;
        __builtin_amdgcn_global_load_lds(
            (const __attribute__((address_space(1))) void*)gp,
            (__attribute__((address_space(3))) void*)((char*)Bs + wid * 4096 + it * 1024),
            16, 0, 0);
      }
    }
    __syncthreads();
    const char* Ab = (const char*)As;
    const char* Bb = (const char*)Bs;
    #pragma unroll
    for (int kk = 0; kk < 2; kk++) {
      short8 a[4], b[4];
      #pragma unroll
      for (int m = 0; m < 4; m++) {
        int row = wr * 64 + m * 16 + lr;
        int off = (row << 7) + kk * 64 + lk * 16;
        off ^= (row & 7) << 4;
        a[m] = *(const short8*)(Ab + off);
      }
      #pragma unroll
      for (int n = 0; n < 4; n++) {
        int row = wc * 64 + n * 16 + lr;
        int off = (row << 7) + kk * 64 + lk * 16;
        off ^= (row & 7) << 4;
        b[n] = *(const short8*)(Bb + off);
      }
      #pragma unroll
      for (int m = 0; m < 4; m++)
        #pragma unroll
        for (int n = 0; n < 4; n++)
          acc[m][n] = __builtin_amdgcn_mfma_f32_16x16x32_bf16(a[m], b[n], acc[m][n], 0, 0, 0);
    }
    __syncthreads();
  }

  #pragma unroll
  for (int m = 0; m < 4; m++)
    #pragma unroll
    for (int n = 0; n < 4; n++)
      #pragma unroll
      for (int r = 0; r < 4; r++) {
        int row = r0 + wr * 64 + m * 16 + lk * 4 + r;
        if (row < M) {
          int col = c0 + wc * 64 + n * 16 + lr;
          C[(size_t)row * Nc + col] = f2b(acc[m][n][r]);
        }
      }
}

// ---------------- attention projections (bf16 input) ----------------
__global__ void k_att_h4(const u16* __restrict__ hm, const float* __restrict__ att_s,
                         const float* __restrict__ att_d, float* __restrict__ s_out,
                         float* __restrict__ d_out, int N) {
  int wid = blockIdx.x * (blockDim.x >> 6) + (threadIdx.x >> 6);
  int lane = threadIdx.x & 63;
  if (wid >= N) return;
  const u16* row = hm + (size_t)wid * HC;
  float ps[HEADS], pd[HEADS];
  #pragma unroll
  for (int hh = 0; hh < HEADS; hh++) {
    float x0 = b2f(row[hh * CH + lane]), x1 = b2f(row[hh * CH + 64 + lane]);
    ps[hh] = x0 * att_s[hh * CH + lane] + x1 * att_s[hh * CH + 64 + lane];
    pd[hh] = x0 * att_d[hh * CH + lane] + x1 * att_d[hh * CH + 64 + lane];
  }
  #pragma unroll
  for (int off = 32; off; off >>= 1) {
    #pragma unroll
    for (int hh = 0; hh < HEADS; hh++) {
      ps[hh] += __shfl_xor(ps[hh], off);
      pd[hh] += __shfl_xor(pd[hh], off);
    }
  }
  if (lane == 0) {
    #pragma unroll
    for (int hh = 0; hh < HEADS; hh++) {
      s_out[wid * HEADS + hh] = ps[hh];
      d_out[wid * HEADS + hh] = pd[hh];
    }
  }
}

__global__ void k_att_h1(const u16* __restrict__ hm, const float* __restrict__ att_s,
                         const float* __restrict__ att_d, float* __restrict__ s_out,
                         float* __restrict__ d_out, int N) {
  int wid = blockIdx.x * (blockDim.x >> 6) + (threadIdx.x >> 6);
  int lane = threadIdx.x & 63;
  if (wid >= N) return;
  const u16* row = hm + (size_t)wid * CH;
  float x0 = b2f(row[lane]), x1 = b2f(row[64 + lane]);
  float ps = x0 * att_s[lane] + x1 * att_s[64 + lane];
  float pd = x0 * att_d[lane] + x1 * att_d[64 + lane];
  #pragma unroll
  for (int off = 32; off; off >>= 1) {
    ps += __shfl_xor(ps, off);
    pd += __shfl_xor(pd, off);
  }
  if (lane == 0) { s_out[wid] = ps; d_out[wid] = pd; }
}

// ---------------- conv1: fused segment-softmax + aggregate + bias + LN + ReLU ----------------
// h gathered as bf16 (dword = 2 channels per thread); math in fp32; writes bf16 h1.
__global__ __launch_bounds__(256) void k_agg1(
    const u16* __restrict__ hm, const int* __restrict__ indptr,
    const int* __restrict__ srcs, const float* __restrict__ as1,
    const float* __restrict__ ad1, const float* __restrict__ bias,
    const float* __restrict__ gam, const float* __restrict__ bet,
    u16* __restrict__ out, int N) {
  int n = blockIdx.x;
  if (n >= N) return;
  int t = threadIdx.x;
  int lane = t & 63, wid = t >> 6;
  int beg = indptr[n], end = indptr[n + 1];
  __shared__ float s_wmax[4][HEADS];
  __shared__ float s_max[HEADS];
  __shared__ float s_den[HEADS];
  __shared__ int s_src[64];
  __shared__ float s_w[64][HEADS];
  __shared__ float2 s_red[256];
  float ad[HEADS];
  #pragma unroll
  for (int hh = 0; hh < HEADS; hh++) ad[hh] = ad1[n * HEADS + hh];
  // phase 1: per-head max of leaky_relu scores
  float mx[HEADS] = {-1e30f, -1e30f, -1e30f, -1e30f};
  for (int e = beg + t; e < end; e += 256) {
    int s = srcs[e];
    #pragma unroll
    for (int hh = 0; hh < HEADS; hh++) {
      float v = as1[s * HEADS + hh] + ad[hh];
      v = v > 0.f ? v : 0.2f * v;
      mx[hh] = fmaxf(mx[hh], v);
    }
  }
  #pragma unroll
  for (int off = 32; off; off >>= 1)
    #pragma unroll
    for (int hh = 0; hh < HEADS; hh++)
      mx[hh] = fmaxf(mx[hh], __shfl_xor(mx[hh], off));
  if (lane == 0)
    #pragma unroll
    for (int hh = 0; hh < HEADS; hh++) s_wmax[wid][hh] = mx[hh];
  __syncthreads();
  if (t < HEADS)
    s_max[t] = fmaxf(fmaxf(s_wmax[0][t], s_wmax[1][t]), fmaxf(s_wmax[2][t], s_wmax[3][t]));
  __syncthreads();
  // phase 2: exp weights + weighted aggregate (2 bf16 channels per thread)
  int hA = t >> 6;                 // head of channels 2t,2t+1
  int myh = t & 3;
  float mymax = s_max[myh];
  float dsum = 0.f, acc0 = 0.f, acc1 = 0.f;
  const u32* hmd = (const u32*)hm;
  for (int base = beg; base < end; base += 64) {
    int cnt = min(64, end - base);
    if (t < cnt * 4) {
      int j = t >> 2;
      int s = srcs[base + j];
      if (myh == 0) s_src[j] = s;
      float v = as1[s * HEADS + myh] + ad[myh];
      v = v > 0.f ? v : 0.2f * v;
      float w = __expf(v - mymax);
      s_w[j][myh] = w;
      dsum += w;
    }
    __syncthreads();
    #pragma unroll 4
    for (int j = 0; j < cnt; j++) {
      u32 d = hmd[(size_t)s_src[j] * 256 + t];
      float w = s_w[j][hA];
      acc0 += w * __uint_as_float(d << 16);
      acc1 += w * __uint_as_float(d & 0xffff0000u);
    }
    __syncthreads();
  }
  // denominators per head
  s_red[t].x = dsum;
  __syncthreads();
  if (t < HEADS) {
    float dd = 0.f;
    for (int q = t; q < 256; q += 4) dd += s_red[q].x;
    s_den[t] = dd + 1e-16f;
  }
  __syncthreads();
  float v0 = acc0 / s_den[hA] + bias[2 * t];
  float v1 = acc1 / s_den[hA] + bias[2 * t + 1];
  __syncthreads();
  // LayerNorm over 512 channels
  s_red[t] = make_float2(v0 + v1, v0 * v0 + v1 * v1);
  __syncthreads();
  for (int off = 128; off; off >>= 1) {
    if (t < off) {
      s_red[t].x += s_red[t + off].x;
      s_red[t].y += s_red[t + off].y;
    }
    __syncthreads();
  }
  float mean = s_red[0].x * (1.f / 512.f);
  float var = s_red[0].y * (1.f / 512.f) - mean * mean;
  float rs = rsqrtf(var + 1e-5f);
  float y0 = fmaxf((v0 - mean) * rs * gam[2 * t] + bet[2 * t], 0.f);
  float y1 = fmaxf((v1 - mean) * rs * gam[2 * t + 1] + bet[2 * t + 1], 0.f);
  ((u32*)out)[(size_t)n * 256 + t] = (u32)f2b(y0) | ((u32)f2b(y1) << 16);
}

// ---------------- conv2: 1 head, 128 channels (bf16 gather, fp32 out) ----------------
__global__ __launch_bounds__(128) void k_agg2(
    const u16* __restrict__ hm, const int* __restrict__ indptr,
    const int* __restrict__ srcs, const float* __restrict__ as2,
    const float* __restrict__ ad2, const float* __restrict__ bias,
    const float* __restrict__ gam, const float* __restrict__ bet,
    float* __restrict__ out, int N) {
  int n = blockIdx.x;
  if (n >= N) return;
  int t = threadIdx.x;
  int lane = t & 63, wid = t >> 6;
  int beg = indptr[n], end = indptr[n + 1];
  __shared__ float s_wmax[2];
  __shared__ int s_src[128];
  __shared__ float s_w[128];
  __shared__ float2 s_red[128];
  __shared__ float s_comb[64][2];
  float adv = ad2[n];
  float mx = -1e30f;
  for (int e = beg + t; e < end; e += 128) {
    float v = as2[srcs[e]] + adv;
    v = v > 0.f ? v : 0.2f * v;
    mx = fmaxf(mx, v);
  }
  #pragma unroll
  for (int off = 32; off; off >>= 1) mx = fmaxf(mx, __shfl_xor(mx, off));
  if (lane == 0) s_wmax[wid] = mx;
  __syncthreads();
  float m = fmaxf(s_wmax[0], s_wmax[1]);
  int sub = t >> 6;     // edge parity
  int cidx = t & 63;    // dword index in 128-ch row
  float dsum = 0.f, acc0 = 0.f, acc1 = 0.f;
  const u32* hmd = (const u32*)hm;
  for (int base = beg; base < end; base += 128) {
    int cnt = min(128, end - base);
    if (t < cnt) {
      int s = srcs[base + t];
      s_src[t] = s;
      float v = as2[s] + adv;
      v = v > 0.f ? v : 0.2f * v;
      float w = __expf(v - m);
      s_w[t] = w;
      dsum += w;
    }
    __syncthreads();
    #pragma unroll 4
    for (int jb = 0; jb < cnt; jb += 2) {
      int j = jb + sub;
      if (j < cnt) {
        u32 d = hmd[(size_t)s_src[j] * 64 + cidx];
        float w = s_w[j];
        acc0 += w * __uint_as_float(d << 16);
        acc1 += w * __uint_as_float(d & 0xffff0000u);
      }
    }
    __syncthreads();
  }
  s_red[t].x = dsum;
  __syncthreads();
  for (int off = 64; off; off >>= 1) {
    if (t < off) s_red[t].x += s_red[t + off].x;
    __syncthreads();
  }
  float den = s_red[0].x + 1e-16f;
  __syncthreads();
  if (sub) { s_comb[cidx][0] = acc0; s_comb[cidx][1] = acc1; }
  __syncthreads();
  float v0 = 0.f, v1 = 0.f;
  if (!sub) {
    acc0 += s_comb[cidx][0];
    acc1 += s_comb[cidx][1];
    v0 = acc0 / den + bias[2 * cidx];
    v1 = acc1 / den + bias[2 * cidx + 1];
    s_red[cidx] = make_float2(v0 + v1, v0 * v0 + v1 * v1);
  }
  __syncthreads();
  for (int off = 32; off; off >>= 1) {
    if (t < off) {
      s_red[t].x += s_red[t + off].x;
      s_red[t].y += s_red[t + off].y;
    }
    __syncthreads();
  }
  float mean = s_red[0].x * (1.f / 128.f);
  float var = s_red[0].y * (1.f / 128.f) - mean * mean;
  float rs = rsqrtf(var + 1e-5f);
  if (!sub) {
    float y0 = fmaxf((v0 - mean) * rs * gam[2 * cidx] + bet[2 * cidx], 0.f);
    float y1 = fmaxf((v1 - mean) * rs * gam[2 * cidx + 1] + bet[2 * cidx + 1], 0.f);
    ((float2*)out)[(size_t)n * 64 + cidx] = make_float2(y0, y1);
  }
}

// ---------------- global mean pool ----------------
__global__ void k_pool(const float* __restrict__ h2, const int* __restrict__ batch,
                       float* __restrict__ psum, int N) {
  int i = blockIdx.x * blockDim.x + threadIdx.x;
  if (i >= N * CH) return;
  int n = i >> 7;
  atomicAdd(&psum[(size_t)batch[n] * CH + (i & 127)], h2[i]);
}

__global__ void k_cnt(const int* __restrict__ batch, int* __restrict__ pcnt, int N) {
  int i = blockIdx.x * blockDim.x + threadIdx.x;
  if (i < N) atomicAdd(&pcnt[batch[i]], 1);
}

// ---------------- MLP head ----------------
__global__ __launch_bounds__(128) void k_head(const float* __restrict__ psum,
    const int* __restrict__ pcnt, const float* __restrict__ rW1, const float* __restrict__ rb1,
    const float* __restrict__ rg, const float* __restrict__ rbe,
    const float* __restrict__ rW2, const float* __restrict__ rb2,
    float* __restrict__ outp) {
  int g = blockIdx.x, t = threadIdx.x;
  __shared__ float pl[128];
  __shared__ float yv[32];
  __shared__ float rv[32];
  __shared__ float mv[2];
  float cnt = fmaxf((float)pcnt[g], 1.f);
  pl[t] = psum[g * 128 + t] / cnt;
  __syncthreads();
  if (t < 32) {
    float s = rb1[t];
    for (int c = 0; c < 128; c++) s += pl[c] * rW1[c * 32 + t];
    yv[t] = s;
  }
  __syncthreads();
  if (t == 0) {
    float s = 0.f, sq = 0.f;
    for (int j = 0; j < 32; j++) { s += yv[j]; sq += yv[j] * yv[j]; }
    float mean = s / 32.f;
    float var = sq / 32.f - mean * mean;
    mv[0] = mean; mv[1] = rsqrtf(var + 1e-5f);
  }
  __syncthreads();
  if (t < 32) {
    float y = (yv[t] - mv[0]) * mv[1] * rg[t] + rbe[t];
    rv[t] = fmaxf(y, 0.f);
  }
  __syncthreads();
  if (t < OUT_DIM) {
    float s = rb2[t];
    for (int j = 0; j < 32; j++) s += rv[j] * rW2[j * 8 + t];
    outp[g * 8 + t] = s;
  }
}

extern "C" void kernel_launch(void* const* d_in, const int* in_sizes, int n_in,
                              void* d_out, int out_size, void* d_ws, size_t ws_size,
                              hipStream_t stream) {
  const float* x    = (const float*)d_in[0];
  const int*   ei   = (const int*)d_in[1];
  const int*   batch= (const int*)d_in[3];
  const float* W1   = (const float*)d_in[4];
  const float* as1w = (const float*)d_in[5];
  const float* ad1w = (const float*)d_in[6];
  const float* b1   = (const float*)d_in[7];
  const float* g1   = (const float*)d_in[8];
  const float* be1  = (const float*)d_in[9];
  const float* W2   = (const float*)d_in[10];
  const float* as2w = (const float*)d_in[11];
  const float* ad2w = (const float*)d_in[12];
  const float* b2   = (const float*)d_in[13];
  const float* g2   = (const float*)d_in[14];
  const float* be2  = (const float*)d_in[15];
  const float* rW1  = (const float*)d_in[16];
  const float* rb1  = (const float*)d_in[17];
  const float* rg   = (const float*)d_in[18];
  const float* rbe  = (const float*)d_in[19];
  const float* rW2  = (const float*)d_in[20];
  const float* rb2  = (const float*)d_in[21];

  int N = in_sizes[0] / 128;
  int E = in_sizes[1] / 2;
  int ET = E + N;

  char* p = (char*)d_ws;
  u16* x_b   = (u16*)p; p += (size_t)N * 128 * 2;
  u16* h_b   = (u16*)p; p += (size_t)N * 512 * 2;
  u16* h1_b  = (u16*)p; p += (size_t)N * 512 * 2;
  u16* raw2b = (u16*)p; p += (size_t)N * 128 * 2;
  float* h2  = (float*)p; p += (size_t)N * 128 * 4;
  u16* W1t   = (u16*)p; p += 512 * 128 * 2;
  u16* W2t   = (u16*)p; p += 128 * 512 * 2;
  float* sa1 = (float*)p; p += (size_t)N * 4 * 4;
  float* da1 = (float*)p; p += (size_t)N * 4 * 4;
  float* sa2 = (float*)p; p += (size_t)N * 4;
  float* da2 = (float*)p; p += (size_t)N * 4;
  float* psum = (float*)p; p += GRAPHS * CH * 4;
  int* pcnt   = (int*)p; p += GRAPHS * 4;
  int* counts = (int*)p; p += (size_t)N * 4;
  int* indptr = (int*)p; p += (size_t)(N + 1) * 4;
  int* cursor = (int*)p; p += (size_t)N * 4;
  int* srcs   = (int*)p; p += (size_t)ET * 4;

  hipMemsetAsync(counts, 0, (size_t)N * sizeof(int), stream);
  hipMemsetAsync(psum, 0, (size_t)GRAPHS * CH * sizeof(float), stream);
  hipMemsetAsync(pcnt, 0, (size_t)GRAPHS * sizeof(int), stream);

  int eb = (ET + 255) / 256;
  k_count<<<eb, 256, 0, stream>>>(ei, counts, E, N);
  k_scan<<<1, 1024, 0, stream>>>(counts, indptr, cursor, N);
  k_scatter<<<eb, 256, 0, stream>>>(ei, cursor, srcs, E, N);

  // conversions
  k_f2b<<<(N * 64 + 255) / 256, 256, 0, stream>>>(x, (u32*)x_b, N * 64);
  k_wt<<<(512 * 128 + 255) / 256, 256, 0, stream>>>(W1, W1t, 128, 512);
  k_wt<<<(512 * 128 + 255) / 256, 256, 0, stream>>>(W2, W2t, 512, 128);

  // conv1
  dim3 grid1((N + 127) / 128, 4);
  k_gemm_bf16<<<grid1, 256, 0, stream>>>(x_b, W1t, h_b, N, 512, 128);
  k_att_h4<<<(N + 3) / 4, 256, 0, stream>>>(h_b, as1w, ad1w, sa1, da1, N);
  k_agg1<<<N, 256, 0, stream>>>(h_b, indptr, srcs, sa1, da1, b1, g1, be1, h1_b, N);

  // conv2
  dim3 grid2((N + 127) / 128, 1);
  k_gemm_bf16<<<grid2, 256, 0, stream>>>(h1_b, W2t, raw2b, N, 128, 512);
  k_att_h1<<<(N + 3) / 4, 256, 0, stream>>>(raw2b, as2w, ad2w, sa2, da2, N);
  k_agg2<<<N, 128, 0, stream>>>(raw2b, indptr, srcs, sa2, da2, b2, g2, be2, h2, N);

  // pool + head
  k_pool<<<(N * CH + 255) / 256, 256, 0, stream>>>(h2, batch, psum, N);
  k_cnt<<<(N + 255) / 256, 256, 0, stream>>>(batch, pcnt, N);
  k_head<<<GRAPHS, 128, 0, stream>>>(psum, pcnt, rW1, rb1, rg, rbe, rW2, rb2, (float*)d_out);
}

// Round 3
// 725.476 us; speedup vs baseline: 1.3148x; 1.0525x over previous
//
#include <hip/hip_runtime.h>
#include <math.h>

#define HEADS 4
#define CH 128
#define HC 512
#define GRAPHS 128
#define OUT_DIM 8

typedef unsigned short u16;
typedef unsigned int u32;
typedef short short8 __attribute__((ext_vector_type(8)));
typedef float f32x4 __attribute__((ext_vector_type(4)));

__device__ inline u16 f2b(float f) {
  u32 u = __float_as_uint(f);
  u32 r = u + 0x7FFFu + ((u >> 16) & 1u);
  return (u16)(r >> 16);
}
__device__ inline float blo(u32 d) { return __uint_as_float(d << 16); }
__device__ inline float bhi(u32 d) { return __uint_as_float(d & 0xffff0000u); }

// ---------------- CSR build ----------------
__global__ void k_count(const int* __restrict__ ei, int* __restrict__ counts, int E, int N) {
  int i = blockIdx.x * blockDim.x + threadIdx.x;
  int total = E + N;
  if (i >= total) return;
  int dst = (i < E) ? ei[E + i] : (i - E);
  atomicAdd(&counts[dst], 1);
}

__global__ __launch_bounds__(256) void k_scanA(const int* __restrict__ counts,
                                               int* __restrict__ bsum, int N) {
  __shared__ int sh[256];
  int b = blockIdx.x, t = threadIdx.x, i = b * 256 + t;
  sh[t] = (i < N) ? counts[i] : 0;
  __syncthreads();
  for (int off = 128; off; off >>= 1) {
    if (t < off) sh[t] += sh[t + off];
    __syncthreads();
  }
  if (t == 0) bsum[b] = sh[0];
}

__global__ __launch_bounds__(1024) void k_scanB(const int* __restrict__ bsum,
                                                int* __restrict__ boff, int nb) {
  __shared__ int sh[1024];
  int t = threadIdx.x;
  sh[t] = (t < nb) ? bsum[t] : 0;
  __syncthreads();
  for (int off = 1; off < 1024; off <<= 1) {
    int v = sh[t];
    int u = (t >= off) ? sh[t - off] : 0;
    __syncthreads();
    sh[t] = v + u;
    __syncthreads();
  }
  if (t < nb) boff[t] = (t == 0) ? 0 : sh[t - 1];
}

__global__ __launch_bounds__(256) void k_scanC(const int* __restrict__ counts,
                                               const int* __restrict__ boff,
                                               int* __restrict__ indptr,
                                               int* __restrict__ cursor, int N) {
  __shared__ int sh[256];
  int b = blockIdx.x, t = threadIdx.x, i = b * 256 + t;
  int v = (i < N) ? counts[i] : 0;
  sh[t] = v;
  __syncthreads();
  for (int off = 1; off < 256; off <<= 1) {
    int a = sh[t];
    int u = (t >= off) ? sh[t - off] : 0;
    __syncthreads();
    sh[t] = a + u;
    __syncthreads();
  }
  if (i < N) {
    int excl = boff[b] + sh[t] - v;
    indptr[i] = excl;
    cursor[i] = excl;
    if (i == N - 1) indptr[N] = excl + v;
  }
}

__global__ void k_scatter(const int* __restrict__ ei, int* __restrict__ cursor,
                          int* __restrict__ srcs, int E, int N) {
  int i = blockIdx.x * blockDim.x + threadIdx.x;
  int total = E + N;
  if (i >= total) return;
  int src, dst;
  if (i < E) { src = ei[i]; dst = ei[E + i]; } else { src = i - E; dst = i - E; }
  int pos = atomicAdd(&cursor[dst], 1);
  srcs[pos] = src;
}

// ---------------- converters ----------------
__global__ void k_f2b(const float* __restrict__ in, u32* __restrict__ out, int n2) {
  int i = blockIdx.x * blockDim.x + threadIdx.x;
  if (i >= n2) return;
  float2 v = ((const float2*)in)[i];
  out[i] = (u32)f2b(v.x) | ((u32)f2b(v.y) << 16);
}

// W [K][Nc] fp32 -> Wt [Nc][K] bf16 (transposed)
__global__ void k_wt(const float* __restrict__ W, u16* __restrict__ Wt, int K, int Nc) {
  int i = blockIdx.x * blockDim.x + threadIdx.x;
  if (i >= K * Nc) return;
  int n = i / K, k = i - n * K;
  Wt[i] = f2b(W[(size_t)k * Nc + n]);
}

// ws[k][o]: o in 0..3 = src heads, 4..7 = dst heads.  ws = W1_head @ att_head
__global__ __launch_bounds__(256) void k_ws(const float* __restrict__ W1,
                                            const float* __restrict__ as1,
                                            const float* __restrict__ ad1,
                                            float* __restrict__ ws) {
  int t = threadIdx.x;
  #pragma unroll
  for (int r = 0; r < 4; r++) {
    int idx = r * 256 + t;       // 0..1023
    int k = idx >> 3, o = idx & 7, h = o & 3;
    const float* av = ((o < 4) ? as1 : ad1) + h * CH;
    const float* wrow = W1 + (size_t)k * HC + h * CH;
    float s = 0.f;
    for (int c = 0; c < CH; c++) s += wrow[c] * av[c];
    ws[idx] = s;
  }
}

// scores from fp32 x: one wave per node, 8 dots of length 128
__global__ void k_score1(const float* __restrict__ x, const float* __restrict__ ws,
                         float* __restrict__ sa1, float* __restrict__ da1, int N) {
  int n = blockIdx.x * (blockDim.x >> 6) + (threadIdx.x >> 6);
  int lane = threadIdx.x & 63;
  if (n >= N) return;
  const float* row = x + (size_t)n * 128;
  float x0 = row[lane], x1 = row[64 + lane];
  float p[8];
  #pragma unroll
  for (int o = 0; o < 8; o++)
    p[o] = x0 * ws[lane * 8 + o] + x1 * ws[(64 + lane) * 8 + o];
  #pragma unroll
  for (int off = 32; off; off >>= 1)
    #pragma unroll
    for (int o = 0; o < 8; o++) p[o] += __shfl_xor(p[o], off);
  if (lane == 0) {
    #pragma unroll
    for (int h = 0; h < 4; h++) {
      sa1[n * 4 + h] = p[h];
      da1[n * 4 + h] = p[4 + h];
    }
  }
}

// ---------------- conv1 aggregation over x (bf16), 4 heads ----------------
__global__ __launch_bounds__(256) void k_aggx(
    const u32* __restrict__ xb, const int* __restrict__ indptr,
    const int* __restrict__ srcs, const float* __restrict__ as1,
    const float* __restrict__ ad1, u32* __restrict__ aggx, int N) {
  int n = blockIdx.x;
  if (n >= N) return;
  int t = threadIdx.x;
  int lane = t & 63, wid = t >> 6;
  int beg = indptr[n], end = indptr[n + 1];
  __shared__ float s_wmax[4][4];
  __shared__ float s_max[4];
  __shared__ float s_den[4];
  __shared__ int s_src[64];
  __shared__ __align__(16) float s_w[64][4];
  __shared__ float s_red[256];
  __shared__ float s_comb[4][512];
  float ad[4];
  #pragma unroll
  for (int h = 0; h < 4; h++) ad[h] = ad1[n * 4 + h];
  // phase 1: per-head max
  float mx[4] = {-1e30f, -1e30f, -1e30f, -1e30f};
  for (int e = beg + t; e < end; e += 256) {
    int s = srcs[e];
    #pragma unroll
    for (int h = 0; h < 4; h++) {
      float v = as1[s * 4 + h] + ad[h];
      v = v > 0.f ? v : 0.2f * v;
      mx[h] = fmaxf(mx[h], v);
    }
  }
  #pragma unroll
  for (int off = 32; off; off >>= 1)
    #pragma unroll
    for (int h = 0; h < 4; h++) mx[h] = fmaxf(mx[h], __shfl_xor(mx[h], off));
  if (lane == 0)
    #pragma unroll
    for (int h = 0; h < 4; h++) s_wmax[wid][h] = mx[h];
  __syncthreads();
  if (t < 4)
    s_max[t] = fmaxf(fmaxf(s_wmax[0][t], s_wmax[1][t]), fmaxf(s_wmax[2][t], s_wmax[3][t]));
  __syncthreads();
  // phase 2: weights + gather x rows, 4 edges in parallel (one per wave)
  int myh = t & 3;
  float mymax = s_max[myh];
  float dsum = 0.f;
  float acc[4][2] = {};
  for (int base = beg; base < end; base += 64) {
    int cnt = min(64, end - base);
    __syncthreads();
    if (t < cnt * 4) {
      int j = t >> 2;
      int s = srcs[base + j];
      if (myh == 0) s_src[j] = s;
      float v = as1[s * 4 + myh] + ad[myh];
      v = v > 0.f ? v : 0.2f * v;
      float w = __expf(v - mymax);
      s_w[j][myh] = w;
      dsum += w;
    }
    __syncthreads();
    for (int j0 = 0; j0 < cnt; j0 += 4) {
      int j = j0 + wid;
      if (j < cnt) {
        u32 d = xb[(size_t)s_src[j] * 64 + lane];
        float x0 = blo(d), x1 = bhi(d);
        float4 w4 = *(const float4*)&s_w[j][0];
        acc[0][0] += w4.x * x0; acc[0][1] += w4.x * x1;
        acc[1][0] += w4.y * x0; acc[1][1] += w4.y * x1;
        acc[2][0] += w4.z * x0; acc[2][1] += w4.z * x1;
        acc[3][0] += w4.w * x0; acc[3][1] += w4.w * x1;
      }
    }
  }
  s_red[t] = dsum;
  __syncthreads();
  if (t < 4) {
    float dd = 0.f;
    for (int q = t; q < 256; q += 4) dd += s_red[q];
    s_den[t] = 1.f / (dd + 1e-16f);
  }
  #pragma unroll
  for (int h = 0; h < 4; h++) {
    s_comb[wid][h * 128 + 2 * lane] = acc[h][0];
    s_comb[wid][h * 128 + 2 * lane + 1] = acc[h][1];
  }
  __syncthreads();
  int hh = t >> 6, c2 = t & 63;
  int ch = hh * 128 + 2 * c2;
  float inv = s_den[hh];
  float v0 = (s_comb[0][ch] + s_comb[1][ch] + s_comb[2][ch] + s_comb[3][ch]) * inv;
  float v1 = (s_comb[0][ch + 1] + s_comb[1][ch + 1] + s_comb[2][ch + 1] + s_comb[3][ch + 1]) * inv;
  aggx[(size_t)n * 256 + t] = (u32)f2b(v0) | ((u32)f2b(v1) << 16);
}

// ---------------- per-head GEMM: raw1[:, hC:(h+1)C] = aggx[:,h,:] @ W1[:,hC:(h+1)C] + b1 ----------------
__global__ __launch_bounds__(256) void k_gemm_head(
    const u16* __restrict__ A,    // aggx [M][512]
    const u16* __restrict__ Bt,   // W1t  [512][128]
    const float* __restrict__ bias,
    u16* __restrict__ C,          // raw1 [M][512]
    int M) {
  __shared__ u16 As[128 * 64];
  __shared__ u16 Bs[128 * 64];
  int t = threadIdx.x;
  int lane = t & 63, wid = t >> 6;
  int wr = wid >> 1, wc = wid & 1;
  int r0 = blockIdx.x * 128;
  int hh = blockIdx.y;
  const u16* Ah = A + hh * 128;
  const u16* Bh = Bt + (size_t)hh * 128 * 128;
  int lr = lane & 15, lk = lane >> 4;
  f32x4 acc[4][4] = {};
  for (int kt = 0; kt < 128; kt += 64) {
    #pragma unroll
    for (int it = 0; it < 4; it++) {
      int q = wid * 4096 + it * 1024 + lane * 16;
      int row = q >> 7;
      int soff = ((q >> 4) & 7) ^ (row & 7);
      {
        int gr = r0 + row; if (gr >= M) gr = M - 1;
        const u16* gp = Ah + (size_t)gr * 512 + kt + soff * 8;
        __builtin_amdgcn_global_load_lds(
            (const __attribute__((address_space(1))) void*)gp,
            (__attribute__((address_space(3))) void*)((char*)As + wid * 4096 + it * 1024),
            16, 0, 0);
      }
      {
        const u16* gp = Bh + (size_t)row * 128 + kt + soff * 8;
        __builtin_amdgcn_global_load_lds(
            (const __attribute__((address_space(1))) void*)gp,
            (__attribute__((address_space(3))) void*)((char*)Bs + wid * 4096 + it * 1024),
            16, 0, 0);
      }
    }
    __syncthreads();
    const char* Ab = (const char*)As;
    const char* Bb = (const char*)Bs;
    #pragma unroll
    for (int kk = 0; kk < 2; kk++) {
      short8 a[4], b[4];
      #pragma unroll
      for (int m = 0; m < 4; m++) {
        int row = wr * 64 + m * 16 + lr;
        int off = (row << 7) + kk * 64 + lk * 16;
        off ^= (row & 7) << 4;
        a[m] = *(const short8*)(Ab + off);
      }
      #pragma unroll
      for (int nn = 0; nn < 4; nn++) {
        int row = wc * 64 + nn * 16 + lr;
        int off = (row << 7) + kk * 64 + lk * 16;
        off ^= (row & 7) << 4;
        b[nn] = *(const short8*)(Bb + off);
      }
      #pragma unroll
      for (int m = 0; m < 4; m++)
        #pragma unroll
        for (int nn = 0; nn < 4; nn++)
          acc[m][nn] = __builtin_amdgcn_mfma_f32_16x16x32_bf16(a[m], b[nn], acc[m][nn], 0, 0, 0);
    }
    __syncthreads();
  }
  #pragma unroll
  for (int m = 0; m < 4; m++)
    #pragma unroll
    for (int nn = 0; nn < 4; nn++)
      #pragma unroll
      for (int r = 0; r < 4; r++) {
        int row = r0 + wr * 64 + m * 16 + lk * 4 + r;
        if (row < M) {
          int gcol = hh * 128 + wc * 64 + nn * 16 + lr;
          C[(size_t)row * 512 + gcol] = f2b(acc[m][nn][r] + bias[gcol]);
        }
      }
}

// ---------------- LN+ReLU over 512 channels (bf16 in/out) ----------------
__global__ __launch_bounds__(256) void k_ln512(const u16* __restrict__ raw,
                                               const float* __restrict__ gam,
                                               const float* __restrict__ bet,
                                               u16* __restrict__ out, int N) {
  int n = blockIdx.x * 4 + (threadIdx.x >> 6);
  int lane = threadIdx.x & 63;
  if (n >= N) return;
  const uint4* r = (const uint4*)(raw + (size_t)n * 512);
  uint4 q = r[lane];
  float v[8];
  v[0] = blo(q.x); v[1] = bhi(q.x); v[2] = blo(q.y); v[3] = bhi(q.y);
  v[4] = blo(q.z); v[5] = bhi(q.z); v[6] = blo(q.w); v[7] = bhi(q.w);
  float s1 = 0.f, s2 = 0.f;
  #pragma unroll
  for (int j = 0; j < 8; j++) { s1 += v[j]; s2 += v[j] * v[j]; }
  #pragma unroll
  for (int off = 32; off; off >>= 1) {
    s1 += __shfl_xor(s1, off);
    s2 += __shfl_xor(s2, off);
  }
  float mean = s1 * (1.f / 512.f);
  float var = s2 * (1.f / 512.f) - mean * mean;
  float rs = rsqrtf(var + 1e-5f);
  u32 o[4];
  #pragma unroll
  for (int j = 0; j < 4; j++) {
    int ch = lane * 8 + 2 * j;
    float y0 = fmaxf((v[2 * j] - mean) * rs * gam[ch] + bet[ch], 0.f);
    float y1 = fmaxf((v[2 * j + 1] - mean) * rs * gam[ch + 1] + bet[ch + 1], 0.f);
    o[j] = (u32)f2b(y0) | ((u32)f2b(y1) << 16);
  }
  ((uint4*)(out + (size_t)n * 512))[lane] = make_uint4(o[0], o[1], o[2], o[3]);
}

// ---------------- bf16 MFMA GEMM (conv2): C[M][128] = A[M][512] * Bt[128][512]^T ----------------
__global__ __launch_bounds__(256) void k_gemm_bf16(
    const u16* __restrict__ A, const u16* __restrict__ Bt,
    u16* __restrict__ C, int M, int Nc, int K) {
  __shared__ u16 As[128 * 64];
  __shared__ u16 Bs[128 * 64];
  int t = threadIdx.x;
  int lane = t & 63, wid = t >> 6;
  int wr = wid >> 1, wc = wid & 1;
  int r0 = blockIdx.x * 128, c0 = blockIdx.y * 128;
  int lr = lane & 15, lk = lane >> 4;
  f32x4 acc[4][4] = {};
  for (int kt = 0; kt < K; kt += 64) {
    #pragma unroll
    for (int it = 0; it < 4; it++) {
      int q = wid * 4096 + it * 1024 + lane * 16;
      int row = q >> 7;
      int soff = ((q >> 4) & 7) ^ (row & 7);
      {
        int gr = r0 + row; if (gr >= M) gr = M - 1;
        const u16* gp = A + (size_t)gr * K + kt + soff * 8;
        __builtin_amdgcn_global_load_lds(
            (const __attribute__((address_space(1))) void*)gp,
            (__attribute__((address_space(3))) void*)((char*)As + wid * 4096 + it * 1024),
            16, 0, 0);
      }
      {
        int gn = c0 + row;
        const u16* gp = Bt + (size_t)gn * K + kt + soff * 8;
        __builtin_amdgcn_global_load_lds(
            (const __attribute__((address_space(1))) void*)gp,
            (__attribute__((address_space(3))) void*)((char*)Bs + wid * 4096 + it * 1024),
            16, 0, 0);
      }
    }
    __syncthreads();
    const char* Ab = (const char*)As;
    const char* Bb = (const char*)Bs;
    #pragma unroll
    for (int kk = 0; kk < 2; kk++) {
      short8 a[4], b[4];
      #pragma unroll
      for (int m = 0; m < 4; m++) {
        int row = wr * 64 + m * 16 + lr;
        int off = (row << 7) + kk * 64 + lk * 16;
        off ^= (row & 7) << 4;
        a[m] = *(const short8*)(Ab + off);
      }
      #pragma unroll
      for (int nn = 0; nn < 4; nn++) {
        int row = wc * 64 + nn * 16 + lr;
        int off = (row << 7) + kk * 64 + lk * 16;
        off ^= (row & 7) << 4;
        b[nn] = *(const short8*)(Bb + off);
      }
      #pragma unroll
      for (int m = 0; m < 4; m++)
        #pragma unroll
        for (int nn = 0; nn < 4; nn++)
          acc[m][nn] = __builtin_amdgcn_mfma_f32_16x16x32_bf16(a[m], b[nn], acc[m][nn], 0, 0, 0);
    }
    __syncthreads();
  }
  #pragma unroll
  for (int m = 0; m < 4; m++)
    #pragma unroll
    for (int nn = 0; nn < 4; nn++)
      #pragma unroll
      for (int r = 0; r < 4; r++) {
        int row = r0 + wr * 64 + m * 16 + lk * 4 + r;
        if (row < M) {
          int col = c0 + wc * 64 + nn * 16 + lr;
          C[(size_t)row * Nc + col] = f2b(acc[m][nn][r]);
        }
      }
}

// ---------------- conv2 scores ----------------
__global__ void k_att_h1(const u16* __restrict__ hm, const float* __restrict__ att_s,
                         const float* __restrict__ att_d, float* __restrict__ s_out,
                         float* __restrict__ d_out, int N) {
  int n = blockIdx.x * (blockDim.x >> 6) + (threadIdx.x >> 6);
  int lane = threadIdx.x & 63;
  if (n >= N) return;
  const u32* row = (const u32*)(hm + (size_t)n * CH);
  u32 d = row[lane];
  float x0 = blo(d), x1 = bhi(d);
  float ps = x0 * att_s[2 * lane] + x1 * att_s[2 * lane + 1];
  float pd = x0 * att_d[2 * lane] + x1 * att_d[2 * lane + 1];
  #pragma unroll
  for (int off = 32; off; off >>= 1) {
    ps += __shfl_xor(ps, off);
    pd += __shfl_xor(pd, off);
  }
  if (lane == 0) { s_out[n] = ps; d_out[n] = pd; }
}

// ---------------- conv2 aggregation + bias + LN + ReLU + pool atomics ----------------
__global__ __launch_bounds__(256) void k_agg2f(
    const u32* __restrict__ raw2, const int* __restrict__ indptr,
    const int* __restrict__ srcs, const float* __restrict__ as2,
    const float* __restrict__ ad2, const float* __restrict__ bias,
    const float* __restrict__ gam, const float* __restrict__ bet,
    const int* __restrict__ batch, float* __restrict__ psum, int N) {
  int n = blockIdx.x;
  if (n >= N) return;
  int t = threadIdx.x;
  int lane = t & 63, wid = t >> 6;
  int beg = indptr[n], end = indptr[n + 1];
  __shared__ float s_wmax[4];
  __shared__ int s_src[64];
  __shared__ float s_w[64];
  __shared__ float s_red[256];
  __shared__ float s_comb[4][128];
  float adv = ad2[n];
  float mx = -1e30f;
  for (int e = beg + t; e < end; e += 256) {
    float v = as2[srcs[e]] + adv;
    v = v > 0.f ? v : 0.2f * v;
    mx = fmaxf(mx, v);
  }
  #pragma unroll
  for (int off = 32; off; off >>= 1) mx = fmaxf(mx, __shfl_xor(mx, off));
  if (lane == 0) s_wmax[wid] = mx;
  __syncthreads();
  float m = fmaxf(fmaxf(s_wmax[0], s_wmax[1]), fmaxf(s_wmax[2], s_wmax[3]));
  float dsum = 0.f, a0 = 0.f, a1 = 0.f;
  for (int base = beg; base < end; base += 64) {
    int cnt = min(64, end - base);
    __syncthreads();
    if (t < cnt) {
      int s = srcs[base + t];
      s_src[t] = s;
      float v = as2[s] + adv;
      v = v > 0.f ? v : 0.2f * v;
      float w = __expf(v - m);
      s_w[t] = w;
      dsum += w;
    }
    __syncthreads();
    for (int j0 = 0; j0 < cnt; j0 += 4) {
      int j = j0 + wid;
      if (j < cnt) {
        u32 d = raw2[(size_t)s_src[j] * 64 + lane];
        float w = s_w[j];
        a0 += w * blo(d);
        a1 += w * bhi(d);
      }
    }
  }
  s_red[t] = dsum;
  __syncthreads();
  for (int off = 128; off; off >>= 1) {
    if (t < off) s_red[t] += s_red[t + off];
    __syncthreads();
  }
  float den = s_red[0] + 1e-16f;
  s_comb[wid][2 * lane] = a0;
  s_comb[wid][2 * lane + 1] = a1;
  __syncthreads();
  if (t < 64) {
    float v0 = (s_comb[0][2 * t] + s_comb[1][2 * t] + s_comb[2][2 * t] + s_comb[3][2 * t]) / den
               + bias[2 * t];
    float v1 = (s_comb[0][2 * t + 1] + s_comb[1][2 * t + 1] + s_comb[2][2 * t + 1]
                + s_comb[3][2 * t + 1]) / den + bias[2 * t + 1];
    float s1 = v0 + v1, s2 = v0 * v0 + v1 * v1;
    #pragma unroll
    for (int off = 32; off; off >>= 1) {
      s1 += __shfl_xor(s1, off);
      s2 += __shfl_xor(s2, off);
    }
    float mean = s1 * (1.f / 128.f);
    float var = s2 * (1.f / 128.f) - mean * mean;
    float rs = rsqrtf(var + 1e-5f);
    float y0 = fmaxf((v0 - mean) * rs * gam[2 * t] + bet[2 * t], 0.f);
    float y1 = fmaxf((v1 - mean) * rs * gam[2 * t + 1] + bet[2 * t + 1], 0.f);
    int g = batch[n];
    atomicAdd(&psum[g * 128 + 2 * t], y0);
    atomicAdd(&psum[g * 128 + 2 * t + 1], y1);
  }
}

// ---------------- graph node counts + MLP head ----------------
__global__ void k_cnt(const int* __restrict__ batch, int* __restrict__ pcnt, int N) {
  int i = blockIdx.x * blockDim.x + threadIdx.x;
  if (i < N) atomicAdd(&pcnt[batch[i]], 1);
}

__global__ __launch_bounds__(128) void k_head(const float* __restrict__ psum,
    const int* __restrict__ pcnt, const float* __restrict__ rW1, const float* __restrict__ rb1,
    const float* __restrict__ rg, const float* __restrict__ rbe,
    const float* __restrict__ rW2, const float* __restrict__ rb2,
    float* __restrict__ outp) {
  int g = blockIdx.x, t = threadIdx.x;
  __shared__ float pl[128];
  __shared__ float yv[32];
  __shared__ float rv[32];
  __shared__ float mv[2];
  float cnt = fmaxf((float)pcnt[g], 1.f);
  pl[t] = psum[g * 128 + t] / cnt;
  __syncthreads();
  if (t < 32) {
    float s = rb1[t];
    for (int c = 0; c < 128; c++) s += pl[c] * rW1[c * 32 + t];
    yv[t] = s;
  }
  __syncthreads();
  if (t == 0) {
    float s = 0.f, sq = 0.f;
    for (int j = 0; j < 32; j++) { s += yv[j]; sq += yv[j] * yv[j]; }
    float mean = s / 32.f;
    float var = sq / 32.f - mean * mean;
    mv[0] = mean; mv[1] = rsqrtf(var + 1e-5f);
  }
  __syncthreads();
  if (t < 32) {
    float y = (yv[t] - mv[0]) * mv[1] * rg[t] + rbe[t];
    rv[t] = fmaxf(y, 0.f);
  }
  __syncthreads();
  if (t < OUT_DIM) {
    float s = rb2[t];
    for (int j = 0; j < 32; j++) s += rv[j] * rW2[j * 8 + t];
    outp[g * 8 + t] = s;
  }
}

extern "C" void kernel_launch(void* const* d_in, const int* in_sizes, int n_in,
                              void* d_out, int out_size, void* d_ws, size_t ws_size,
                              hipStream_t stream) {
  const float* x    = (const float*)d_in[0];
  const int*   ei   = (const int*)d_in[1];
  const int*   batch= (const int*)d_in[3];
  const float* W1   = (const float*)d_in[4];
  const float* as1w = (const float*)d_in[5];
  const float* ad1w = (const float*)d_in[6];
  const float* b1   = (const float*)d_in[7];
  const float* g1   = (const float*)d_in[8];
  const float* be1  = (const float*)d_in[9];
  const float* W2   = (const float*)d_in[10];
  const float* as2w = (const float*)d_in[11];
  const float* ad2w = (const float*)d_in[12];
  const float* b2   = (const float*)d_in[13];
  const float* g2   = (const float*)d_in[14];
  const float* be2  = (const float*)d_in[15];
  const float* rW1  = (const float*)d_in[16];
  const float* rb1  = (const float*)d_in[17];
  const float* rg   = (const float*)d_in[18];
  const float* rbe  = (const float*)d_in[19];
  const float* rW2  = (const float*)d_in[20];
  const float* rb2  = (const float*)d_in[21];

  int N = in_sizes[0] / 128;
  int E = in_sizes[1] / 2;
  int ET = E + N;
  int nb = (N + 255) / 256;

  char* p = (char*)d_ws;
  u16* x_b   = (u16*)p; p += (size_t)N * 128 * 2;
  u16* aggx  = (u16*)p; p += (size_t)N * 512 * 2;
  u16* raw1  = (u16*)p; p += (size_t)N * 512 * 2;
  u16* h1_b  = (u16*)p; p += (size_t)N * 512 * 2;
  u16* raw2b = (u16*)p; p += (size_t)N * 128 * 2;
  u16* W1t   = (u16*)p; p += 512 * 128 * 2;
  u16* W2t   = (u16*)p; p += 128 * 512 * 2;
  float* ws  = (float*)p; p += 128 * 8 * 4;
  float* sa1 = (float*)p; p += (size_t)N * 4 * 4;
  float* da1 = (float*)p; p += (size_t)N * 4 * 4;
  float* sa2 = (float*)p; p += (size_t)N * 4;
  float* da2 = (float*)p; p += (size_t)N * 4;
  float* psum = (float*)p; p += GRAPHS * CH * 4;
  int* pcnt   = (int*)p; p += GRAPHS * 4;
  int* counts = (int*)p; p += (size_t)N * 4;
  int* indptr = (int*)p; p += (size_t)(N + 1) * 4;
  int* cursor = (int*)p; p += (size_t)N * 4;
  int* bsum   = (int*)p; p += (size_t)nb * 4;
  int* boff   = (int*)p; p += (size_t)nb * 4;
  int* srcs   = (int*)p; p += (size_t)ET * 4;

  hipMemsetAsync(counts, 0, (size_t)N * sizeof(int), stream);
  hipMemsetAsync(psum, 0, (size_t)GRAPHS * CH * sizeof(float), stream);
  hipMemsetAsync(pcnt, 0, (size_t)GRAPHS * sizeof(int), stream);

  int eb = (ET + 255) / 256;
  k_count<<<eb, 256, 0, stream>>>(ei, counts, E, N);
  k_scanA<<<nb, 256, 0, stream>>>(counts, bsum, N);
  k_scanB<<<1, 1024, 0, stream>>>(bsum, boff, nb);
  k_scanC<<<nb, 256, 0, stream>>>(counts, boff, indptr, cursor, N);
  k_scatter<<<eb, 256, 0, stream>>>(ei, cursor, srcs, E, N);

  // conversions + score matrices
  k_f2b<<<(N * 64 + 255) / 256, 256, 0, stream>>>(x, (u32*)x_b, N * 64);
  k_wt<<<(512 * 128 + 255) / 256, 256, 0, stream>>>(W1, W1t, 128, 512);
  k_wt<<<(512 * 128 + 255) / 256, 256, 0, stream>>>(W2, W2t, 512, 128);
  k_ws<<<1, 256, 0, stream>>>(W1, as1w, ad1w, ws);
  k_score1<<<(N + 3) / 4, 256, 0, stream>>>(x, ws, sa1, da1, N);

  // conv1: aggregate x, then per-head GEMM (+bias), then LN+ReLU
  k_aggx<<<N, 256, 0, stream>>>((const u32*)x_b, indptr, srcs, sa1, da1, (u32*)aggx, N);
  dim3 gridh((N + 127) / 128, 4);
  k_gemm_head<<<gridh, 256, 0, stream>>>(aggx, W1t, b1, raw1, N);
  k_ln512<<<(N + 3) / 4, 256, 0, stream>>>(raw1, g1, be1, h1_b, N);

  // conv2
  dim3 grid2((N + 127) / 128, 1);
  k_gemm_bf16<<<grid2, 256, 0, stream>>>(h1_b, W2t, raw2b, N, 128, 512);
  k_att_h1<<<(N + 3) / 4, 256, 0, stream>>>(raw2b, as2w, ad2w, sa2, da2, N);
  k_agg2f<<<N, 256, 0, stream>>>((const u32*)raw2b, indptr, srcs, sa2, da2, b2, g2, be2,
                                 batch, psum, N);

  // head
  k_cnt<<<(N + 255) / 256, 256, 0, stream>>>(batch, pcnt, N);
  k_head<<<GRAPHS, 128, 0, stream>>>(psum, pcnt, rW1, rb1, rg, rbe, rW2, rb2, (float*)d_out);
}

// Round 4
// 566.138 us; speedup vs baseline: 1.6849x; 1.2814x over previous
//
#include <hip/hip_runtime.h>
#include <math.h>

#define HEADS 4
#define CH 128
#define HC 512
#define GRAPHS 128
#define OUT_DIM 8

typedef unsigned short u16;
typedef unsigned int u32;
typedef short short8 __attribute__((ext_vector_type(8)));
typedef float f32x4 __attribute__((ext_vector_type(4)));

__device__ inline u16 f2b(float f) {
  u32 u = __float_as_uint(f);
  u32 r = u + 0x7FFFu + ((u >> 16) & 1u);
  return (u16)(r >> 16);
}
__device__ inline float blo(u32 d) { return __uint_as_float(d << 16); }
__device__ inline float bhi(u32 d) { return __uint_as_float(d & 0xffff0000u); }
__device__ inline float lrelu(float v) { return v > 0.f ? v : 0.2f * v; }

// ---------------- CSR build ----------------
__global__ void k_count(const int* __restrict__ ei, int* __restrict__ counts, int E, int N) {
  int i = blockIdx.x * blockDim.x + threadIdx.x;
  int total = E + N;
  if (i >= total) return;
  int dst = (i < E) ? ei[E + i] : (i - E);
  atomicAdd(&counts[dst], 1);
}

__global__ __launch_bounds__(256) void k_scanA(const int* __restrict__ counts,
                                               int* __restrict__ bsum, int N) {
  __shared__ int sh[256];
  int b = blockIdx.x, t = threadIdx.x, i = b * 256 + t;
  sh[t] = (i < N) ? counts[i] : 0;
  __syncthreads();
  for (int off = 128; off; off >>= 1) {
    if (t < off) sh[t] += sh[t + off];
    __syncthreads();
  }
  if (t == 0) bsum[b] = sh[0];
}

__global__ __launch_bounds__(1024) void k_scanB(const int* __restrict__ bsum,
                                                int* __restrict__ boff, int nb) {
  __shared__ int sh[1024];
  int t = threadIdx.x;
  sh[t] = (t < nb) ? bsum[t] : 0;
  __syncthreads();
  for (int off = 1; off < 1024; off <<= 1) {
    int v = sh[t];
    int u = (t >= off) ? sh[t - off] : 0;
    __syncthreads();
    sh[t] = v + u;
    __syncthreads();
  }
  if (t < nb) boff[t] = (t == 0) ? 0 : sh[t - 1];
}

__global__ __launch_bounds__(256) void k_scanC(const int* __restrict__ counts,
                                               const int* __restrict__ boff,
                                               int* __restrict__ indptr,
                                               int* __restrict__ cursor, int N) {
  __shared__ int sh[256];
  int b = blockIdx.x, t = threadIdx.x, i = b * 256 + t;
  int v = (i < N) ? counts[i] : 0;
  sh[t] = v;
  __syncthreads();
  for (int off = 1; off < 256; off <<= 1) {
    int a = sh[t];
    int u = (t >= off) ? sh[t - off] : 0;
    __syncthreads();
    sh[t] = a + u;
    __syncthreads();
  }
  if (i < N) {
    int excl = boff[b] + sh[t] - v;
    indptr[i] = excl;
    cursor[i] = excl;
    if (i == N - 1) indptr[N] = excl + v;
  }
}

__global__ void k_scatter(const int* __restrict__ ei, int* __restrict__ cursor,
                          int* __restrict__ srcs, int E, int N) {
  int i = blockIdx.x * blockDim.x + threadIdx.x;
  int total = E + N;
  if (i >= total) return;
  int src, dst;
  if (i < E) { src = ei[i]; dst = ei[E + i]; } else { src = i - E; dst = i - E; }
  int pos = atomicAdd(&cursor[dst], 1);
  srcs[pos] = src;
}

// ---------------- converters ----------------
__global__ void k_f2b(const float* __restrict__ in, u32* __restrict__ out, int n2) {
  int i = blockIdx.x * blockDim.x + threadIdx.x;
  if (i >= n2) return;
  float2 v = ((const float2*)in)[i];
  out[i] = (u32)f2b(v.x) | ((u32)f2b(v.y) << 16);
}

// W [K][Nc] fp32 -> Wt [Nc][K] bf16 (transposed)
__global__ void k_wt(const float* __restrict__ W, u16* __restrict__ Wt, int K, int Nc) {
  int i = blockIdx.x * blockDim.x + threadIdx.x;
  if (i >= K * Nc) return;
  int n = i / K, k = i - n * K;
  Wt[i] = f2b(W[(size_t)k * Nc + n]);
}

// ws[k][o]: o in 0..3 = src heads, 4..7 = dst heads.  ws = W1_head @ att_head
__global__ __launch_bounds__(256) void k_ws(const float* __restrict__ W1,
                                            const float* __restrict__ as1,
                                            const float* __restrict__ ad1,
                                            float* __restrict__ ws) {
  int t = threadIdx.x;
  #pragma unroll
  for (int r = 0; r < 4; r++) {
    int idx = r * 256 + t;       // 0..1023
    int k = idx >> 3, o = idx & 7, h = o & 3;
    const float* av = ((o < 4) ? as1 : ad1) + h * CH;
    const float* wrow = W1 + (size_t)k * HC + h * CH;
    float s = 0.f;
    for (int c = 0; c < CH; c++) s += wrow[c] * av[c];
    ws[idx] = s;
  }
}

// scores from fp32 x: one wave per node, 8 dots of length 128
__global__ void k_score1(const float* __restrict__ x, const float* __restrict__ ws,
                         float* __restrict__ sa1, float* __restrict__ da1, int N) {
  int n = blockIdx.x * (blockDim.x >> 6) + (threadIdx.x >> 6);
  int lane = threadIdx.x & 63;
  if (n >= N) return;
  const float* row = x + (size_t)n * 128;
  float x0 = row[lane], x1 = row[64 + lane];
  float p[8];
  #pragma unroll
  for (int o = 0; o < 8; o++)
    p[o] = x0 * ws[lane * 8 + o] + x1 * ws[(64 + lane) * 8 + o];
  #pragma unroll
  for (int off = 32; off; off >>= 1)
    #pragma unroll
    for (int o = 0; o < 8; o++) p[o] += __shfl_xor(p[o], off);
  if (lane == 0) {
    #pragma unroll
    for (int h = 0; h < 4; h++) {
      sa1[n * 4 + h] = p[h];
      da1[n * 4 + h] = p[4 + h];
    }
  }
}

// ---------------- conv1 aggregation over x (bf16), 4 heads, WAVE PER NODE ----------------
__global__ __launch_bounds__(256) void k_aggx(
    const u32* __restrict__ xb, const int* __restrict__ indptr,
    const int* __restrict__ srcs, const float4* __restrict__ as1,
    const float4* __restrict__ ad1, u32* __restrict__ aggx, int N) {
  int n = blockIdx.x * 4 + (threadIdx.x >> 6);
  if (n >= N) return;
  int lane = threadIdx.x & 63;
  int beg = indptr[n], end = indptr[n + 1];
  float4 ad = ad1[n];
  // pass 1: per-head max
  float m0 = -1e30f, m1 = -1e30f, m2 = -1e30f, m3 = -1e30f;
  for (int base = beg; base < end; base += 64) {
    int e = base + lane;
    if (e < end) {
      float4 a = as1[srcs[e]];
      m0 = fmaxf(m0, lrelu(a.x + ad.x));
      m1 = fmaxf(m1, lrelu(a.y + ad.y));
      m2 = fmaxf(m2, lrelu(a.z + ad.z));
      m3 = fmaxf(m3, lrelu(a.w + ad.w));
    }
  }
  #pragma unroll
  for (int off = 32; off; off >>= 1) {
    m0 = fmaxf(m0, __shfl_xor(m0, off));
    m1 = fmaxf(m1, __shfl_xor(m1, off));
    m2 = fmaxf(m2, __shfl_xor(m2, off));
    m3 = fmaxf(m3, __shfl_xor(m3, off));
  }
  // pass 2: weights in lane regs + gather with shfl broadcast
  float ds0 = 0.f, ds1 = 0.f, ds2 = 0.f, ds3 = 0.f;
  float a00 = 0.f, a01 = 0.f, a10 = 0.f, a11 = 0.f;
  float a20 = 0.f, a21 = 0.f, a30 = 0.f, a31 = 0.f;
  for (int base = beg; base < end; base += 64) {
    int cnt = min(64, end - base);
    int sreg = 0;
    float w0 = 0.f, w1 = 0.f, w2 = 0.f, w3 = 0.f;
    if (lane < cnt) {
      sreg = srcs[base + lane];
      float4 a = as1[sreg];
      w0 = __expf(lrelu(a.x + ad.x) - m0);
      w1 = __expf(lrelu(a.y + ad.y) - m1);
      w2 = __expf(lrelu(a.z + ad.z) - m2);
      w3 = __expf(lrelu(a.w + ad.w) - m3);
      ds0 += w0; ds1 += w1; ds2 += w2; ds3 += w3;
    }
    int j = 0;
    for (; j + 2 <= cnt; j += 2) {
      int sA = __shfl(sreg, j), sB = __shfl(sreg, j + 1);
      u32 dA = xb[(size_t)sA * 64 + lane];
      u32 dB = xb[(size_t)sB * 64 + lane];
      float w0A = __shfl(w0, j), w1A = __shfl(w1, j);
      float w2A = __shfl(w2, j), w3A = __shfl(w3, j);
      float w0B = __shfl(w0, j + 1), w1B = __shfl(w1, j + 1);
      float w2B = __shfl(w2, j + 1), w3B = __shfl(w3, j + 1);
      float xA0 = blo(dA), xA1 = bhi(dA);
      float xB0 = blo(dB), xB1 = bhi(dB);
      a00 += w0A * xA0 + w0B * xB0; a01 += w0A * xA1 + w0B * xB1;
      a10 += w1A * xA0 + w1B * xB0; a11 += w1A * xA1 + w1B * xB1;
      a20 += w2A * xA0 + w2B * xB0; a21 += w2A * xA1 + w2B * xB1;
      a30 += w3A * xA0 + w3B * xB0; a31 += w3A * xA1 + w3B * xB1;
    }
    if (j < cnt) {
      int sA = __shfl(sreg, j);
      u32 dA = xb[(size_t)sA * 64 + lane];
      float w0A = __shfl(w0, j), w1A = __shfl(w1, j);
      float w2A = __shfl(w2, j), w3A = __shfl(w3, j);
      float xA0 = blo(dA), xA1 = bhi(dA);
      a00 += w0A * xA0; a01 += w0A * xA1;
      a10 += w1A * xA0; a11 += w1A * xA1;
      a20 += w2A * xA0; a21 += w2A * xA1;
      a30 += w3A * xA0; a31 += w3A * xA1;
    }
  }
  #pragma unroll
  for (int off = 32; off; off >>= 1) {
    ds0 += __shfl_xor(ds0, off);
    ds1 += __shfl_xor(ds1, off);
    ds2 += __shfl_xor(ds2, off);
    ds3 += __shfl_xor(ds3, off);
  }
  float i0 = 1.f / (ds0 + 1e-16f), i1 = 1.f / (ds1 + 1e-16f);
  float i2 = 1.f / (ds2 + 1e-16f), i3 = 1.f / (ds3 + 1e-16f);
  u32* orow = aggx + (size_t)n * 256;
  orow[lane]       = (u32)f2b(a00 * i0) | ((u32)f2b(a01 * i0) << 16);
  orow[64 + lane]  = (u32)f2b(a10 * i1) | ((u32)f2b(a11 * i1) << 16);
  orow[128 + lane] = (u32)f2b(a20 * i2) | ((u32)f2b(a21 * i2) << 16);
  orow[192 + lane] = (u32)f2b(a30 * i3) | ((u32)f2b(a31 * i3) << 16);
}

// ---------------- per-head GEMM: raw1[:, hC:(h+1)C] = aggx[:,h,:] @ W1[:,hC:(h+1)C] + b1 ----------------
__global__ __launch_bounds__(256) void k_gemm_head(
    const u16* __restrict__ A,    // aggx [M][512]
    const u16* __restrict__ Bt,   // W1t  [512][128]
    const float* __restrict__ bias,
    u16* __restrict__ C,          // raw1 [M][512]
    int M) {
  __shared__ u16 As[128 * 64];
  __shared__ u16 Bs[128 * 64];
  int t = threadIdx.x;
  int lane = t & 63, wid = t >> 6;
  int wr = wid >> 1, wc = wid & 1;
  int r0 = blockIdx.x * 128;
  int hh = blockIdx.y;
  const u16* Ah = A + hh * 128;
  const u16* Bh = Bt + (size_t)hh * 128 * 128;
  int lr = lane & 15, lk = lane >> 4;
  f32x4 acc[4][4] = {};
  for (int kt = 0; kt < 128; kt += 64) {
    #pragma unroll
    for (int it = 0; it < 4; it++) {
      int q = wid * 4096 + it * 1024 + lane * 16;
      int row = q >> 7;
      int soff = ((q >> 4) & 7) ^ (row & 7);
      {
        int gr = r0 + row; if (gr >= M) gr = M - 1;
        const u16* gp = Ah + (size_t)gr * 512 + kt + soff * 8;
        __builtin_amdgcn_global_load_lds(
            (const __attribute__((address_space(1))) void*)gp,
            (__attribute__((address_space(3))) void*)((char*)As + wid * 4096 + it * 1024),
            16, 0, 0);
      }
      {
        const u16* gp = Bh + (size_t)row * 128 + kt + soff * 8;
        __builtin_amdgcn_global_load_lds(
            (const __attribute__((address_space(1))) void*)gp,
            (__attribute__((address_space(3))) void*)((char*)Bs + wid * 4096 + it * 1024),
            16, 0, 0);
      }
    }
    __syncthreads();
    const char* Ab = (const char*)As;
    const char* Bb = (const char*)Bs;
    #pragma unroll
    for (int kk = 0; kk < 2; kk++) {
      short8 a[4], b[4];
      #pragma unroll
      for (int m = 0; m < 4; m++) {
        int row = wr * 64 + m * 16 + lr;
        int off = (row << 7) + kk * 64 + lk * 16;
        off ^= (row & 7) << 4;
        a[m] = *(const short8*)(Ab + off);
      }
      #pragma unroll
      for (int nn = 0; nn < 4; nn++) {
        int row = wc * 64 + nn * 16 + lr;
        int off = (row << 7) + kk * 64 + lk * 16;
        off ^= (row & 7) << 4;
        b[nn] = *(const short8*)(Bb + off);
      }
      #pragma unroll
      for (int m = 0; m < 4; m++)
        #pragma unroll
        for (int nn = 0; nn < 4; nn++)
          acc[m][nn] = __builtin_amdgcn_mfma_f32_16x16x32_bf16(a[m], b[nn], acc[m][nn], 0, 0, 0);
    }
    __syncthreads();
  }
  #pragma unroll
  for (int m = 0; m < 4; m++)
    #pragma unroll
    for (int nn = 0; nn < 4; nn++)
      #pragma unroll
      for (int r = 0; r < 4; r++) {
        int row = r0 + wr * 64 + m * 16 + lk * 4 + r;
        if (row < M) {
          int gcol = hh * 128 + wc * 64 + nn * 16 + lr;
          C[(size_t)row * 512 + gcol] = f2b(acc[m][nn][r] + bias[gcol]);
        }
      }
}

// ---------------- LN+ReLU over 512 channels (bf16 in/out) ----------------
__global__ __launch_bounds__(256) void k_ln512(const u16* __restrict__ raw,
                                               const float* __restrict__ gam,
                                               const float* __restrict__ bet,
                                               u16* __restrict__ out, int N) {
  int n = blockIdx.x * 4 + (threadIdx.x >> 6);
  int lane = threadIdx.x & 63;
  if (n >= N) return;
  const uint4* r = (const uint4*)(raw + (size_t)n * 512);
  uint4 q = r[lane];
  float v[8];
  v[0] = blo(q.x); v[1] = bhi(q.x); v[2] = blo(q.y); v[3] = bhi(q.y);
  v[4] = blo(q.z); v[5] = bhi(q.z); v[6] = blo(q.w); v[7] = bhi(q.w);
  float s1 = 0.f, s2 = 0.f;
  #pragma unroll
  for (int j = 0; j < 8; j++) { s1 += v[j]; s2 += v[j] * v[j]; }
  #pragma unroll
  for (int off = 32; off; off >>= 1) {
    s1 += __shfl_xor(s1, off);
    s2 += __shfl_xor(s2, off);
  }
  float mean = s1 * (1.f / 512.f);
  float var = s2 * (1.f / 512.f) - mean * mean;
  float rs = rsqrtf(var + 1e-5f);
  u32 o[4];
  #pragma unroll
  for (int j = 0; j < 4; j++) {
    int ch = lane * 8 + 2 * j;
    float y0 = fmaxf((v[2 * j] - mean) * rs * gam[ch] + bet[ch], 0.f);
    float y1 = fmaxf((v[2 * j + 1] - mean) * rs * gam[ch + 1] + bet[ch + 1], 0.f);
    o[j] = (u32)f2b(y0) | ((u32)f2b(y1) << 16);
  }
  ((uint4*)(out + (size_t)n * 512))[lane] = make_uint4(o[0], o[1], o[2], o[3]);
}

// ---------------- bf16 MFMA GEMM (conv2): C[M][128] = A[M][512] * Bt[128][512]^T ----------------
__global__ __launch_bounds__(256) void k_gemm_bf16(
    const u16* __restrict__ A, const u16* __restrict__ Bt,
    u16* __restrict__ C, int M, int Nc, int K) {
  __shared__ u16 As[128 * 64];
  __shared__ u16 Bs[128 * 64];
  int t = threadIdx.x;
  int lane = t & 63, wid = t >> 6;
  int wr = wid >> 1, wc = wid & 1;
  int r0 = blockIdx.x * 128, c0 = blockIdx.y * 128;
  int lr = lane & 15, lk = lane >> 4;
  f32x4 acc[4][4] = {};
  for (int kt = 0; kt < K; kt += 64) {
    #pragma unroll
    for (int it = 0; it < 4; it++) {
      int q = wid * 4096 + it * 1024 + lane * 16;
      int row = q >> 7;
      int soff = ((q >> 4) & 7) ^ (row & 7);
      {
        int gr = r0 + row; if (gr >= M) gr = M - 1;
        const u16* gp = A + (size_t)gr * K + kt + soff * 8;
        __builtin_amdgcn_global_load_lds(
            (const __attribute__((address_space(1))) void*)gp,
            (__attribute__((address_space(3))) void*)((char*)As + wid * 4096 + it * 1024),
            16, 0, 0);
      }
      {
        int gn = c0 + row;
        const u16* gp = Bt + (size_t)gn * K + kt + soff * 8;
        __builtin_amdgcn_global_load_lds(
            (const __attribute__((address_space(1))) void*)gp,
            (__attribute__((address_space(3))) void*)((char*)Bs + wid * 4096 + it * 1024),
            16, 0, 0);
      }
    }
    __syncthreads();
    const char* Ab = (const char*)As;
    const char* Bb = (const char*)Bs;
    #pragma unroll
    for (int kk = 0; kk < 2; kk++) {
      short8 a[4], b[4];
      #pragma unroll
      for (int m = 0; m < 4; m++) {
        int row = wr * 64 + m * 16 + lr;
        int off = (row << 7) + kk * 64 + lk * 16;
        off ^= (row & 7) << 4;
        a[m] = *(const short8*)(Ab + off);
      }
      #pragma unroll
      for (int nn = 0; nn < 4; nn++) {
        int row = wc * 64 + nn * 16 + lr;
        int off = (row << 7) + kk * 64 + lk * 16;
        off ^= (row & 7) << 4;
        b[nn] = *(const short8*)(Bb + off);
      }
      #pragma unroll
      for (int m = 0; m < 4; m++)
        #pragma unroll
        for (int nn = 0; nn < 4; nn++)
          acc[m][nn] = __builtin_amdgcn_mfma_f32_16x16x32_bf16(a[m], b[nn], acc[m][nn], 0, 0, 0);
    }
    __syncthreads();
  }
  #pragma unroll
  for (int m = 0; m < 4; m++)
    #pragma unroll
    for (int nn = 0; nn < 4; nn++)
      #pragma unroll
      for (int r = 0; r < 4; r++) {
        int row = r0 + wr * 64 + m * 16 + lk * 4 + r;
        if (row < M) {
          int col = c0 + wc * 64 + nn * 16 + lr;
          C[(size_t)row * Nc + col] = f2b(acc[m][nn][r]);
        }
      }
}

// ---------------- conv2 scores ----------------
__global__ void k_att_h1(const u16* __restrict__ hm, const float* __restrict__ att_s,
                         const float* __restrict__ att_d, float* __restrict__ s_out,
                         float* __restrict__ d_out, int N) {
  int n = blockIdx.x * (blockDim.x >> 6) + (threadIdx.x >> 6);
  int lane = threadIdx.x & 63;
  if (n >= N) return;
  const u32* row = (const u32*)(hm + (size_t)n * CH);
  u32 d = row[lane];
  float x0 = blo(d), x1 = bhi(d);
  float ps = x0 * att_s[2 * lane] + x1 * att_s[2 * lane + 1];
  float pd = x0 * att_d[2 * lane] + x1 * att_d[2 * lane + 1];
  #pragma unroll
  for (int off = 32; off; off >>= 1) {
    ps += __shfl_xor(ps, off);
    pd += __shfl_xor(pd, off);
  }
  if (lane == 0) { s_out[n] = ps; d_out[n] = pd; }
}

// ---------------- conv2 aggregation + bias + LN + ReLU + pool, WAVE PER NODE ----------------
__global__ __launch_bounds__(256) void k_agg2f(
    const u32* __restrict__ raw2, const int* __restrict__ indptr,
    const int* __restrict__ srcs, const float* __restrict__ as2,
    const float* __restrict__ ad2, const float* __restrict__ bias,
    const float* __restrict__ gam, const float* __restrict__ bet,
    const int* __restrict__ batch, float* __restrict__ psum, int N) {
  int n = blockIdx.x * 4 + (threadIdx.x >> 6);
  if (n >= N) return;
  int lane = threadIdx.x & 63;
  int beg = indptr[n], end = indptr[n + 1];
  float adv = ad2[n];
  float mx = -1e30f;
  for (int base = beg; base < end; base += 64) {
    int e = base + lane;
    if (e < end) mx = fmaxf(mx, lrelu(as2[srcs[e]] + adv));
  }
  #pragma unroll
  for (int off = 32; off; off >>= 1) mx = fmaxf(mx, __shfl_xor(mx, off));
  float dsum = 0.f, a0 = 0.f, a1 = 0.f;
  for (int base = beg; base < end; base += 64) {
    int cnt = min(64, end - base);
    int sreg = 0;
    float w = 0.f;
    if (lane < cnt) {
      sreg = srcs[base + lane];
      w = __expf(lrelu(as2[sreg] + adv) - mx);
      dsum += w;
    }
    int j = 0;
    for (; j + 2 <= cnt; j += 2) {
      int sA = __shfl(sreg, j), sB = __shfl(sreg, j + 1);
      u32 dA = raw2[(size_t)sA * 64 + lane];
      u32 dB = raw2[(size_t)sB * 64 + lane];
      float wA = __shfl(w, j), wB = __shfl(w, j + 1);
      a0 += wA * blo(dA) + wB * blo(dB);
      a1 += wA * bhi(dA) + wB * bhi(dB);
    }
    if (j < cnt) {
      int sA = __shfl(sreg, j);
      u32 dA = raw2[(size_t)sA * 64 + lane];
      float wA = __shfl(w, j);
      a0 += wA * blo(dA);
      a1 += wA * bhi(dA);
    }
  }
  #pragma unroll
  for (int off = 32; off; off >>= 1) dsum += __shfl_xor(dsum, off);
  float inv = 1.f / (dsum + 1e-16f);
  float v0 = a0 * inv + bias[2 * lane];
  float v1 = a1 * inv + bias[2 * lane + 1];
  float s1 = v0 + v1, s2 = v0 * v0 + v1 * v1;
  #pragma unroll
  for (int off = 32; off; off >>= 1) {
    s1 += __shfl_xor(s1, off);
    s2 += __shfl_xor(s2, off);
  }
  float mean = s1 * (1.f / 128.f);
  float var = s2 * (1.f / 128.f) - mean * mean;
  float rs = rsqrtf(var + 1e-5f);
  float y0 = fmaxf((v0 - mean) * rs * gam[2 * lane] + bet[2 * lane], 0.f);
  float y1 = fmaxf((v1 - mean) * rs * gam[2 * lane + 1] + bet[2 * lane + 1], 0.f);
  int g = batch[n];
  atomicAdd(&psum[g * 128 + 2 * lane], y0);
  atomicAdd(&psum[g * 128 + 2 * lane + 1], y1);
}

// ---------------- graph node counts + MLP head ----------------
__global__ void k_cnt(const int* __restrict__ batch, int* __restrict__ pcnt, int N) {
  int i = blockIdx.x * blockDim.x + threadIdx.x;
  if (i < N) atomicAdd(&pcnt[batch[i]], 1);
}

__global__ __launch_bounds__(128) void k_head(const float* __restrict__ psum,
    const int* __restrict__ pcnt, const float* __restrict__ rW1, const float* __restrict__ rb1,
    const float* __restrict__ rg, const float* __restrict__ rbe,
    const float* __restrict__ rW2, const float* __restrict__ rb2,
    float* __restrict__ outp) {
  int g = blockIdx.x, t = threadIdx.x;
  __shared__ float pl[128];
  __shared__ float yv[32];
  __shared__ float rv[32];
  __shared__ float mv[2];
  float cnt = fmaxf((float)pcnt[g], 1.f);
  pl[t] = psum[g * 128 + t] / cnt;
  __syncthreads();
  if (t < 32) {
    float s = rb1[t];
    for (int c = 0; c < 128; c++) s += pl[c] * rW1[c * 32 + t];
    yv[t] = s;
  }
  __syncthreads();
  if (t == 0) {
    float s = 0.f, sq = 0.f;
    for (int j = 0; j < 32; j++) { s += yv[j]; sq += yv[j] * yv[j]; }
    float mean = s / 32.f;
    float var = sq / 32.f - mean * mean;
    mv[0] = mean; mv[1] = rsqrtf(var + 1e-5f);
  }
  __syncthreads();
  if (t < 32) {
    float y = (yv[t] - mv[0]) * mv[1] * rg[t] + rbe[t];
    rv[t] = fmaxf(y, 0.f);
  }
  __syncthreads();
  if (t < OUT_DIM) {
    float s = rb2[t];
    for (int j = 0; j < 32; j++) s += rv[j] * rW2[j * 8 + t];
    outp[g * 8 + t] = s;
  }
}

extern "C" void kernel_launch(void* const* d_in, const int* in_sizes, int n_in,
                              void* d_out, int out_size, void* d_ws, size_t ws_size,
                              hipStream_t stream) {
  const float* x    = (const float*)d_in[0];
  const int*   ei   = (const int*)d_in[1];
  const int*   batch= (const int*)d_in[3];
  const float* W1   = (const float*)d_in[4];
  const float* as1w = (const float*)d_in[5];
  const float* ad1w = (const float*)d_in[6];
  const float* b1   = (const float*)d_in[7];
  const float* g1   = (const float*)d_in[8];
  const float* be1  = (const float*)d_in[9];
  const float* W2   = (const float*)d_in[10];
  const float* as2w = (const float*)d_in[11];
  const float* ad2w = (const float*)d_in[12];
  const float* b2   = (const float*)d_in[13];
  const float* g2   = (const float*)d_in[14];
  const float* be2  = (const float*)d_in[15];
  const float* rW1  = (const float*)d_in[16];
  const float* rb1  = (const float*)d_in[17];
  const float* rg   = (const float*)d_in[18];
  const float* rbe  = (const float*)d_in[19];
  const float* rW2  = (const float*)d_in[20];
  const float* rb2  = (const float*)d_in[21];

  int N = in_sizes[0] / 128;
  int E = in_sizes[1] / 2;
  int ET = E + N;
  int nb = (N + 255) / 256;

  char* p = (char*)d_ws;
  u16* x_b   = (u16*)p; p += (size_t)N * 128 * 2;
  u16* aggx  = (u16*)p; p += (size_t)N * 512 * 2;
  u16* raw1  = (u16*)p; p += (size_t)N * 512 * 2;
  u16* h1_b  = (u16*)p; p += (size_t)N * 512 * 2;
  u16* raw2b = (u16*)p; p += (size_t)N * 128 * 2;
  u16* W1t   = (u16*)p; p += 512 * 128 * 2;
  u16* W2t   = (u16*)p; p += 128 * 512 * 2;
  float* ws  = (float*)p; p += 128 * 8 * 4;
  float* sa1 = (float*)p; p += (size_t)N * 4 * 4;
  float* da1 = (float*)p; p += (size_t)N * 4 * 4;
  float* sa2 = (float*)p; p += (size_t)N * 4;
  float* da2 = (float*)p; p += (size_t)N * 4;
  float* psum = (float*)p; p += GRAPHS * CH * 4;
  int* pcnt   = (int*)p; p += GRAPHS * 4;
  int* counts = (int*)p; p += (size_t)N * 4;
  int* indptr = (int*)p; p += (size_t)(N + 1) * 4;
  int* cursor = (int*)p; p += (size_t)N * 4;
  int* bsum   = (int*)p; p += (size_t)nb * 4;
  int* boff   = (int*)p; p += (size_t)nb * 4;
  int* srcs   = (int*)p; p += (size_t)ET * 4;

  hipMemsetAsync(counts, 0, (size_t)N * sizeof(int), stream);
  hipMemsetAsync(psum, 0, (size_t)GRAPHS * CH * sizeof(float), stream);
  hipMemsetAsync(pcnt, 0, (size_t)GRAPHS * sizeof(int), stream);

  int eb = (ET + 255) / 256;
  k_count<<<eb, 256, 0, stream>>>(ei, counts, E, N);
  k_scanA<<<nb, 256, 0, stream>>>(counts, bsum, N);
  k_scanB<<<1, 1024, 0, stream>>>(bsum, boff, nb);
  k_scanC<<<nb, 256, 0, stream>>>(counts, boff, indptr, cursor, N);
  k_scatter<<<eb, 256, 0, stream>>>(ei, cursor, srcs, E, N);

  // conversions + score matrices
  k_f2b<<<(N * 64 + 255) / 256, 256, 0, stream>>>(x, (u32*)x_b, N * 64);
  k_wt<<<(512 * 128 + 255) / 256, 256, 0, stream>>>(W1, W1t, 128, 512);
  k_wt<<<(512 * 128 + 255) / 256, 256, 0, stream>>>(W2, W2t, 512, 128);
  k_ws<<<1, 256, 0, stream>>>(W1, as1w, ad1w, ws);
  k_score1<<<(N + 3) / 4, 256, 0, stream>>>(x, ws, sa1, da1, N);

  // conv1: aggregate x (wave per node), per-head GEMM (+bias), LN+ReLU
  k_aggx<<<(N + 3) / 4, 256, 0, stream>>>((const u32*)x_b, indptr, srcs,
                                          (const float4*)sa1, (const float4*)da1,
                                          (u32*)aggx, N);
  dim3 gridh((N + 127) / 128, 4);
  k_gemm_head<<<gridh, 256, 0, stream>>>(aggx, W1t, b1, raw1, N);
  k_ln512<<<(N + 3) / 4, 256, 0, stream>>>(raw1, g1, be1, h1_b, N);

  // conv2
  dim3 grid2((N + 127) / 128, 1);
  k_gemm_bf16<<<grid2, 256, 0, stream>>>(h1_b, W2t, raw2b, N, 128, 512);
  k_att_h1<<<(N + 3) / 4, 256, 0, stream>>>(raw2b, as2w, ad2w, sa2, da2, N);
  k_agg2f<<<(N + 3) / 4, 256, 0, stream>>>((const u32*)raw2b, indptr, srcs, sa2, da2,
                                           b2, g2, be2, batch, psum, N);

  // head
  k_cnt<<<(N + 255) / 256, 256, 0, stream>>>(batch, pcnt, N);
  k_head<<<GRAPHS, 128, 0, stream>>>(psum, pcnt, rW1, rb1, rg, rbe, rW2, rb2, (float*)d_out);
}

// Round 5
// 448.660 us; speedup vs baseline: 2.1260x; 1.2618x over previous
//
#include <hip/hip_runtime.h>
#include <math.h>

#define HEADS 4
#define CH 128
#define HC 512
#define GRAPHS 128
#define OUT_DIM 8

typedef unsigned short u16;
typedef unsigned int u32;
typedef short short8 __attribute__((ext_vector_type(8)));
typedef float f32x4 __attribute__((ext_vector_type(4)));

__device__ inline u16 f2b(float f) {
  u32 u = __float_as_uint(f);
  u32 r = u + 0x7FFFu + ((u >> 16) & 1u);
  return (u16)(r >> 16);
}
__device__ inline float blo(u32 d) { return __uint_as_float(d << 16); }
__device__ inline float bhi(u32 d) { return __uint_as_float(d & 0xffff0000u); }
__device__ inline float lrelu(float v) { return v > 0.f ? v : 0.2f * v; }

// ---------------- CSR build ----------------
__global__ void k_count(const int* __restrict__ ei, int* __restrict__ counts, int E, int N) {
  int i = blockIdx.x * blockDim.x + threadIdx.x;
  int total = E + N;
  if (i >= total) return;
  int dst = (i < E) ? ei[E + i] : (i - E);
  atomicAdd(&counts[dst], 1);
}

__global__ __launch_bounds__(256) void k_scanA(const int* __restrict__ counts,
                                               int* __restrict__ bsum, int N) {
  __shared__ int sh[256];
  int b = blockIdx.x, t = threadIdx.x, i = b * 256 + t;
  sh[t] = (i < N) ? counts[i] : 0;
  __syncthreads();
  for (int off = 128; off; off >>= 1) {
    if (t < off) sh[t] += sh[t + off];
    __syncthreads();
  }
  if (t == 0) bsum[b] = sh[0];
}

__global__ __launch_bounds__(1024) void k_scanB(const int* __restrict__ bsum,
                                                int* __restrict__ boff, int nb) {
  __shared__ int sh[1024];
  int t = threadIdx.x;
  sh[t] = (t < nb) ? bsum[t] : 0;
  __syncthreads();
  for (int off = 1; off < 1024; off <<= 1) {
    int v = sh[t];
    int u = (t >= off) ? sh[t - off] : 0;
    __syncthreads();
    sh[t] = v + u;
    __syncthreads();
  }
  if (t < nb) boff[t] = (t == 0) ? 0 : sh[t - 1];
}

__global__ __launch_bounds__(256) void k_scanC(const int* __restrict__ counts,
                                               const int* __restrict__ boff,
                                               int* __restrict__ indptr,
                                               int* __restrict__ cursor, int N) {
  __shared__ int sh[256];
  int b = blockIdx.x, t = threadIdx.x, i = b * 256 + t;
  int v = (i < N) ? counts[i] : 0;
  sh[t] = v;
  __syncthreads();
  for (int off = 1; off < 256; off <<= 1) {
    int a = sh[t];
    int u = (t >= off) ? sh[t - off] : 0;
    __syncthreads();
    sh[t] = a + u;
    __syncthreads();
  }
  if (i < N) {
    int excl = boff[b] + sh[t] - v;
    indptr[i] = excl;
    cursor[i] = excl;
    if (i == N - 1) indptr[N] = excl + v;
  }
}

__global__ void k_scatter(const int* __restrict__ ei, int* __restrict__ cursor,
                          int* __restrict__ srcs, int E, int N) {
  int i = blockIdx.x * blockDim.x + threadIdx.x;
  int total = E + N;
  if (i >= total) return;
  int src, dst;
  if (i < E) { src = ei[i]; dst = ei[E + i]; } else { src = i - E; dst = i - E; }
  int pos = atomicAdd(&cursor[dst], 1);
  srcs[pos] = src;
}

// ---------------- converters ----------------
__global__ void k_f2b(const float* __restrict__ in, u32* __restrict__ out, int n2) {
  int i = blockIdx.x * blockDim.x + threadIdx.x;
  if (i >= n2) return;
  float2 v = ((const float2*)in)[i];
  out[i] = (u32)f2b(v.x) | ((u32)f2b(v.y) << 16);
}

// W [K][Nc] fp32 -> Wt [Nc][K] bf16 (transposed)
__global__ void k_wt(const float* __restrict__ W, u16* __restrict__ Wt, int K, int Nc) {
  int i = blockIdx.x * blockDim.x + threadIdx.x;
  if (i >= K * Nc) return;
  int n = i / K, k = i - n * K;
  Wt[i] = f2b(W[(size_t)k * Nc + n]);
}

// ws[k][o]: o in 0..3 = src heads, 4..7 = dst heads.  ws = W1_head @ att_head
__global__ __launch_bounds__(256) void k_ws(const float* __restrict__ W1,
                                            const float* __restrict__ as1,
                                            const float* __restrict__ ad1,
                                            float* __restrict__ ws) {
  int t = threadIdx.x;
  #pragma unroll
  for (int r = 0; r < 4; r++) {
    int idx = r * 256 + t;       // 0..1023
    int k = idx >> 3, o = idx & 7, h = o & 3;
    const float* av = ((o < 4) ? as1 : ad1) + h * CH;
    const float* wrow = W1 + (size_t)k * HC + h * CH;
    float s = 0.f;
    for (int c = 0; c < CH; c++) s += wrow[c] * av[c];
    ws[idx] = s;
  }
}

// scores from fp32 x: one wave per node, 8 dots of length 128
__global__ void k_score1(const float* __restrict__ x, const float* __restrict__ ws,
                         float* __restrict__ sa1, float* __restrict__ da1, int N) {
  int n = blockIdx.x * (blockDim.x >> 6) + (threadIdx.x >> 6);
  int lane = threadIdx.x & 63;
  if (n >= N) return;
  const float* row = x + (size_t)n * 128;
  float x0 = row[lane], x1 = row[64 + lane];
  float p[8];
  #pragma unroll
  for (int o = 0; o < 8; o++)
    p[o] = x0 * ws[lane * 8 + o] + x1 * ws[(64 + lane) * 8 + o];
  #pragma unroll
  for (int off = 32; off; off >>= 1)
    #pragma unroll
    for (int o = 0; o < 8; o++) p[o] += __shfl_xor(p[o], off);
  if (lane == 0) {
    #pragma unroll
    for (int h = 0; h < 4; h++) {
      sa1[n * 4 + h] = p[h];
      da1[n * 4 + h] = p[4 + h];
    }
  }
}

// ---------------- conv1 aggregation over x (bf16), 4 heads, WAVE PER NODE ----------------
__global__ __launch_bounds__(256) void k_aggx(
    const u32* __restrict__ xb, const int* __restrict__ indptr,
    const int* __restrict__ srcs, const float4* __restrict__ as1,
    const float4* __restrict__ ad1, u32* __restrict__ aggx, int N) {
  int n = blockIdx.x * 4 + (threadIdx.x >> 6);
  if (n >= N) return;
  int lane = threadIdx.x & 63;
  int beg = indptr[n], end = indptr[n + 1];
  int deg = end - beg;
  float4 ad = ad1[n];
  float ds0 = 0.f, ds1 = 0.f, ds2 = 0.f, ds3 = 0.f;
  float a00 = 0.f, a01 = 0.f, a10 = 0.f, a11 = 0.f;
  float a20 = 0.f, a21 = 0.f, a30 = 0.f, a31 = 0.f;

  if (deg <= 64) {
    // single pass: edge data lives in lane registers
    int sreg = 0;
    float p0 = -1e30f, p1 = -1e30f, p2 = -1e30f, p3 = -1e30f;
    if (lane < deg) {
      sreg = srcs[beg + lane];
      float4 a = as1[sreg];
      p0 = lrelu(a.x + ad.x); p1 = lrelu(a.y + ad.y);
      p2 = lrelu(a.z + ad.z); p3 = lrelu(a.w + ad.w);
    }
    float m0 = p0, m1 = p1, m2 = p2, m3 = p3;
    #pragma unroll
    for (int off = 32; off; off >>= 1) {
      m0 = fmaxf(m0, __shfl_xor(m0, off));
      m1 = fmaxf(m1, __shfl_xor(m1, off));
      m2 = fmaxf(m2, __shfl_xor(m2, off));
      m3 = fmaxf(m3, __shfl_xor(m3, off));
    }
    float w0 = 0.f, w1 = 0.f, w2 = 0.f, w3 = 0.f;
    if (lane < deg) {
      w0 = __expf(p0 - m0); w1 = __expf(p1 - m1);
      w2 = __expf(p2 - m2); w3 = __expf(p3 - m3);
      ds0 = w0; ds1 = w1; ds2 = w2; ds3 = w3;
    }
    int j = 0;
    for (; j + 4 <= deg; j += 4) {
      int sA = __shfl(sreg, j), sB = __shfl(sreg, j + 1);
      int sC = __shfl(sreg, j + 2), sD = __shfl(sreg, j + 3);
      u32 dA = xb[(size_t)sA * 64 + lane];
      u32 dB = xb[(size_t)sB * 64 + lane];
      u32 dC = xb[(size_t)sC * 64 + lane];
      u32 dD = xb[(size_t)sD * 64 + lane];
      float xA0 = blo(dA), xA1 = bhi(dA), xB0 = blo(dB), xB1 = bhi(dB);
      float xC0 = blo(dC), xC1 = bhi(dC), xD0 = blo(dD), xD1 = bhi(dD);
      float wA, wB, wC, wD;
      wA = __shfl(w0, j); wB = __shfl(w0, j + 1); wC = __shfl(w0, j + 2); wD = __shfl(w0, j + 3);
      a00 += wA * xA0 + wB * xB0 + wC * xC0 + wD * xD0;
      a01 += wA * xA1 + wB * xB1 + wC * xC1 + wD * xD1;
      wA = __shfl(w1, j); wB = __shfl(w1, j + 1); wC = __shfl(w1, j + 2); wD = __shfl(w1, j + 3);
      a10 += wA * xA0 + wB * xB0 + wC * xC0 + wD * xD0;
      a11 += wA * xA1 + wB * xB1 + wC * xC1 + wD * xD1;
      wA = __shfl(w2, j); wB = __shfl(w2, j + 1); wC = __shfl(w2, j + 2); wD = __shfl(w2, j + 3);
      a20 += wA * xA0 + wB * xB0 + wC * xC0 + wD * xD0;
      a21 += wA * xA1 + wB * xB1 + wC * xC1 + wD * xD1;
      wA = __shfl(w3, j); wB = __shfl(w3, j + 1); wC = __shfl(w3, j + 2); wD = __shfl(w3, j + 3);
      a30 += wA * xA0 + wB * xB0 + wC * xC0 + wD * xD0;
      a31 += wA * xA1 + wB * xB1 + wC * xC1 + wD * xD1;
    }
    for (; j < deg; j++) {
      int sA = __shfl(sreg, j);
      u32 dA = xb[(size_t)sA * 64 + lane];
      float xA0 = blo(dA), xA1 = bhi(dA);
      float w0A = __shfl(w0, j), w1A = __shfl(w1, j);
      float w2A = __shfl(w2, j), w3A = __shfl(w3, j);
      a00 += w0A * xA0; a01 += w0A * xA1;
      a10 += w1A * xA0; a11 += w1A * xA1;
      a20 += w2A * xA0; a21 += w2A * xA1;
      a30 += w3A * xA0; a31 += w3A * xA1;
    }
  } else {
    // fallback: chunked two-pass (rare)
    float m0 = -1e30f, m1 = -1e30f, m2 = -1e30f, m3 = -1e30f;
    for (int base = beg; base < end; base += 64) {
      int e = base + lane;
      if (e < end) {
        float4 a = as1[srcs[e]];
        m0 = fmaxf(m0, lrelu(a.x + ad.x));
        m1 = fmaxf(m1, lrelu(a.y + ad.y));
        m2 = fmaxf(m2, lrelu(a.z + ad.z));
        m3 = fmaxf(m3, lrelu(a.w + ad.w));
      }
    }
    #pragma unroll
    for (int off = 32; off; off >>= 1) {
      m0 = fmaxf(m0, __shfl_xor(m0, off));
      m1 = fmaxf(m1, __shfl_xor(m1, off));
      m2 = fmaxf(m2, __shfl_xor(m2, off));
      m3 = fmaxf(m3, __shfl_xor(m3, off));
    }
    for (int base = beg; base < end; base += 64) {
      int cnt = min(64, end - base);
      int sreg = 0;
      float w0 = 0.f, w1 = 0.f, w2 = 0.f, w3 = 0.f;
      if (lane < cnt) {
        sreg = srcs[base + lane];
        float4 a = as1[sreg];
        w0 = __expf(lrelu(a.x + ad.x) - m0);
        w1 = __expf(lrelu(a.y + ad.y) - m1);
        w2 = __expf(lrelu(a.z + ad.z) - m2);
        w3 = __expf(lrelu(a.w + ad.w) - m3);
        ds0 += w0; ds1 += w1; ds2 += w2; ds3 += w3;
      }
      for (int j = 0; j < cnt; j++) {
        int sA = __shfl(sreg, j);
        u32 dA = xb[(size_t)sA * 64 + lane];
        float xA0 = blo(dA), xA1 = bhi(dA);
        float w0A = __shfl(w0, j), w1A = __shfl(w1, j);
        float w2A = __shfl(w2, j), w3A = __shfl(w3, j);
        a00 += w0A * xA0; a01 += w0A * xA1;
        a10 += w1A * xA0; a11 += w1A * xA1;
        a20 += w2A * xA0; a21 += w2A * xA1;
        a30 += w3A * xA0; a31 += w3A * xA1;
      }
    }
  }
  #pragma unroll
  for (int off = 32; off; off >>= 1) {
    ds0 += __shfl_xor(ds0, off);
    ds1 += __shfl_xor(ds1, off);
    ds2 += __shfl_xor(ds2, off);
    ds3 += __shfl_xor(ds3, off);
  }
  float i0 = 1.f / (ds0 + 1e-16f), i1 = 1.f / (ds1 + 1e-16f);
  float i2 = 1.f / (ds2 + 1e-16f), i3 = 1.f / (ds3 + 1e-16f);
  u32* orow = aggx + (size_t)n * 256;
  orow[lane]       = (u32)f2b(a00 * i0) | ((u32)f2b(a01 * i0) << 16);
  orow[64 + lane]  = (u32)f2b(a10 * i1) | ((u32)f2b(a11 * i1) << 16);
  orow[128 + lane] = (u32)f2b(a20 * i2) | ((u32)f2b(a21 * i2) << 16);
  orow[192 + lane] = (u32)f2b(a30 * i3) | ((u32)f2b(a31 * i3) << 16);
}

// ---------------- per-head GEMM: raw1[:, hC:(h+1)C] = aggx[:,h,:] @ W1[:,hC:(h+1)C] + b1 ----------------
__global__ __launch_bounds__(256) void k_gemm_head(
    const u16* __restrict__ A,    // aggx [M][512]
    const u16* __restrict__ Bt,   // W1t  [512][128]
    const float* __restrict__ bias,
    u16* __restrict__ C,          // raw1 [M][512]
    int M) {
  __shared__ u16 As[128 * 64];
  __shared__ u16 Bs[128 * 64];
  int t = threadIdx.x;
  int lane = t & 63, wid = t >> 6;
  int wr = wid >> 1, wc = wid & 1;
  int r0 = blockIdx.x * 128;
  int hh = blockIdx.y;
  const u16* Ah = A + hh * 128;
  const u16* Bh = Bt + (size_t)hh * 128 * 128;
  int lr = lane & 15, lk = lane >> 4;
  f32x4 acc[4][4] = {};
  for (int kt = 0; kt < 128; kt += 64) {
    #pragma unroll
    for (int it = 0; it < 4; it++) {
      int q = wid * 4096 + it * 1024 + lane * 16;
      int row = q >> 7;
      int soff = ((q >> 4) & 7) ^ (row & 7);
      {
        int gr = r0 + row; if (gr >= M) gr = M - 1;
        const u16* gp = Ah + (size_t)gr * 512 + kt + soff * 8;
        __builtin_amdgcn_global_load_lds(
            (const __attribute__((address_space(1))) void*)gp,
            (__attribute__((address_space(3))) void*)((char*)As + wid * 4096 + it * 1024),
            16, 0, 0);
      }
      {
        const u16* gp = Bh + (size_t)row * 128 + kt + soff * 8;
        __builtin_amdgcn_global_load_lds(
            (const __attribute__((address_space(1))) void*)gp,
            (__attribute__((address_space(3))) void*)((char*)Bs + wid * 4096 + it * 1024),
            16, 0, 0);
      }
    }
    __syncthreads();
    const char* Ab = (const char*)As;
    const char* Bb = (const char*)Bs;
    #pragma unroll
    for (int kk = 0; kk < 2; kk++) {
      short8 a[4], b[4];
      #pragma unroll
      for (int m = 0; m < 4; m++) {
        int row = wr * 64 + m * 16 + lr;
        int off = (row << 7) + kk * 64 + lk * 16;
        off ^= (row & 7) << 4;
        a[m] = *(const short8*)(Ab + off);
      }
      #pragma unroll
      for (int nn = 0; nn < 4; nn++) {
        int row = wc * 64 + nn * 16 + lr;
        int off = (row << 7) + kk * 64 + lk * 16;
        off ^= (row & 7) << 4;
        b[nn] = *(const short8*)(Bb + off);
      }
      #pragma unroll
      for (int m = 0; m < 4; m++)
        #pragma unroll
        for (int nn = 0; nn < 4; nn++)
          acc[m][nn] = __builtin_amdgcn_mfma_f32_16x16x32_bf16(a[m], b[nn], acc[m][nn], 0, 0, 0);
    }
    __syncthreads();
  }
  #pragma unroll
  for (int m = 0; m < 4; m++)
    #pragma unroll
    for (int nn = 0; nn < 4; nn++)
      #pragma unroll
      for (int r = 0; r < 4; r++) {
        int row = r0 + wr * 64 + m * 16 + lk * 4 + r;
        if (row < M) {
          int gcol = hh * 128 + wc * 64 + nn * 16 + lr;
          C[(size_t)row * 512 + gcol] = f2b(acc[m][nn][r] + bias[gcol]);
        }
      }
}

// ---------------- LN+ReLU over 512 channels (bf16 in/out) ----------------
__global__ __launch_bounds__(256) void k_ln512(const u16* __restrict__ raw,
                                               const float* __restrict__ gam,
                                               const float* __restrict__ bet,
                                               u16* __restrict__ out, int N) {
  int n = blockIdx.x * 4 + (threadIdx.x >> 6);
  int lane = threadIdx.x & 63;
  if (n >= N) return;
  const uint4* r = (const uint4*)(raw + (size_t)n * 512);
  uint4 q = r[lane];
  float v[8];
  v[0] = blo(q.x); v[1] = bhi(q.x); v[2] = blo(q.y); v[3] = bhi(q.y);
  v[4] = blo(q.z); v[5] = bhi(q.z); v[6] = blo(q.w); v[7] = bhi(q.w);
  float s1 = 0.f, s2 = 0.f;
  #pragma unroll
  for (int j = 0; j < 8; j++) { s1 += v[j]; s2 += v[j] * v[j]; }
  #pragma unroll
  for (int off = 32; off; off >>= 1) {
    s1 += __shfl_xor(s1, off);
    s2 += __shfl_xor(s2, off);
  }
  float mean = s1 * (1.f / 512.f);
  float var = s2 * (1.f / 512.f) - mean * mean;
  float rs = rsqrtf(var + 1e-5f);
  u32 o[4];
  #pragma unroll
  for (int j = 0; j < 4; j++) {
    int ch = lane * 8 + 2 * j;
    float y0 = fmaxf((v[2 * j] - mean) * rs * gam[ch] + bet[ch], 0.f);
    float y1 = fmaxf((v[2 * j + 1] - mean) * rs * gam[ch + 1] + bet[ch + 1], 0.f);
    o[j] = (u32)f2b(y0) | ((u32)f2b(y1) << 16);
  }
  ((uint4*)(out + (size_t)n * 512))[lane] = make_uint4(o[0], o[1], o[2], o[3]);
}

// ---------------- bf16 MFMA GEMM (conv2): C[M][128] = A[M][512] * Bt[128][512]^T ----------------
__global__ __launch_bounds__(256) void k_gemm_bf16(
    const u16* __restrict__ A, const u16* __restrict__ Bt,
    u16* __restrict__ C, int M, int Nc, int K) {
  __shared__ u16 As[128 * 64];
  __shared__ u16 Bs[128 * 64];
  int t = threadIdx.x;
  int lane = t & 63, wid = t >> 6;
  int wr = wid >> 1, wc = wid & 1;
  int r0 = blockIdx.x * 128, c0 = blockIdx.y * 128;
  int lr = lane & 15, lk = lane >> 4;
  f32x4 acc[4][4] = {};
  for (int kt = 0; kt < K; kt += 64) {
    #pragma unroll
    for (int it = 0; it < 4; it++) {
      int q = wid * 4096 + it * 1024 + lane * 16;
      int row = q >> 7;
      int soff = ((q >> 4) & 7) ^ (row & 7);
      {
        int gr = r0 + row; if (gr >= M) gr = M - 1;
        const u16* gp = A + (size_t)gr * K + kt + soff * 8;
        __builtin_amdgcn_global_load_lds(
            (const __attribute__((address_space(1))) void*)gp,
            (__attribute__((address_space(3))) void*)((char*)As + wid * 4096 + it * 1024),
            16, 0, 0);
      }
      {
        int gn = c0 + row;
        const u16* gp = Bt + (size_t)gn * K + kt + soff * 8;
        __builtin_amdgcn_global_load_lds(
            (const __attribute__((address_space(1))) void*)gp,
            (__attribute__((address_space(3))) void*)((char*)Bs + wid * 4096 + it * 1024),
            16, 0, 0);
      }
    }
    __syncthreads();
    const char* Ab = (const char*)As;
    const char* Bb = (const char*)Bs;
    #pragma unroll
    for (int kk = 0; kk < 2; kk++) {
      short8 a[4], b[4];
      #pragma unroll
      for (int m = 0; m < 4; m++) {
        int row = wr * 64 + m * 16 + lr;
        int off = (row << 7) + kk * 64 + lk * 16;
        off ^= (row & 7) << 4;
        a[m] = *(const short8*)(Ab + off);
      }
      #pragma unroll
      for (int nn = 0; nn < 4; nn++) {
        int row = wc * 64 + nn * 16 + lr;
        int off = (row << 7) + kk * 64 + lk * 16;
        off ^= (row & 7) << 4;
        b[nn] = *(const short8*)(Bb + off);
      }
      #pragma unroll
      for (int m = 0; m < 4; m++)
        #pragma unroll
        for (int nn = 0; nn < 4; nn++)
          acc[m][nn] = __builtin_amdgcn_mfma_f32_16x16x32_bf16(a[m], b[nn], acc[m][nn], 0, 0, 0);
    }
    __syncthreads();
  }
  #pragma unroll
  for (int m = 0; m < 4; m++)
    #pragma unroll
    for (int nn = 0; nn < 4; nn++)
      #pragma unroll
      for (int r = 0; r < 4; r++) {
        int row = r0 + wr * 64 + m * 16 + lk * 4 + r;
        if (row < M) {
          int col = c0 + wc * 64 + nn * 16 + lr;
          C[(size_t)row * Nc + col] = f2b(acc[m][nn][r]);
        }
      }
}

// ---------------- conv2 scores ----------------
__global__ void k_att_h1(const u16* __restrict__ hm, const float* __restrict__ att_s,
                         const float* __restrict__ att_d, float* __restrict__ s_out,
                         float* __restrict__ d_out, int N) {
  int n = blockIdx.x * (blockDim.x >> 6) + (threadIdx.x >> 6);
  int lane = threadIdx.x & 63;
  if (n >= N) return;
  const u32* row = (const u32*)(hm + (size_t)n * CH);
  u32 d = row[lane];
  float x0 = blo(d), x1 = bhi(d);
  float ps = x0 * att_s[2 * lane] + x1 * att_s[2 * lane + 1];
  float pd = x0 * att_d[2 * lane] + x1 * att_d[2 * lane + 1];
  #pragma unroll
  for (int off = 32; off; off >>= 1) {
    ps += __shfl_xor(ps, off);
    pd += __shfl_xor(pd, off);
  }
  if (lane == 0) { s_out[n] = ps; d_out[n] = pd; }
}

// ---------------- conv2 aggregation + bias + LN + ReLU + pool, WAVE PER NODE ----------------
__global__ __launch_bounds__(256) void k_agg2f(
    const u32* __restrict__ raw2, const int* __restrict__ indptr,
    const int* __restrict__ srcs, const float* __restrict__ as2,
    const float* __restrict__ ad2, const float* __restrict__ bias,
    const float* __restrict__ gam, const float* __restrict__ bet,
    const int* __restrict__ batch, float* __restrict__ psum, int N) {
  int n = blockIdx.x * 4 + (threadIdx.x >> 6);
  if (n >= N) return;
  int lane = threadIdx.x & 63;
  int beg = indptr[n], end = indptr[n + 1];
  int deg = end - beg;
  float adv = ad2[n];
  float dsum = 0.f, a0 = 0.f, a1 = 0.f;

  if (deg <= 64) {
    int sreg = 0;
    float p = -1e30f;
    if (lane < deg) {
      sreg = srcs[beg + lane];
      p = lrelu(as2[sreg] + adv);
    }
    float mx = p;
    #pragma unroll
    for (int off = 32; off; off >>= 1) mx = fmaxf(mx, __shfl_xor(mx, off));
    float w = 0.f;
    if (lane < deg) { w = __expf(p - mx); dsum = w; }
    int j = 0;
    for (; j + 4 <= deg; j += 4) {
      int sA = __shfl(sreg, j), sB = __shfl(sreg, j + 1);
      int sC = __shfl(sreg, j + 2), sD = __shfl(sreg, j + 3);
      u32 dA = raw2[(size_t)sA * 64 + lane];
      u32 dB = raw2[(size_t)sB * 64 + lane];
      u32 dC = raw2[(size_t)sC * 64 + lane];
      u32 dD = raw2[(size_t)sD * 64 + lane];
      float wA = __shfl(w, j), wB = __shfl(w, j + 1);
      float wC = __shfl(w, j + 2), wD = __shfl(w, j + 3);
      a0 += wA * blo(dA) + wB * blo(dB) + wC * blo(dC) + wD * blo(dD);
      a1 += wA * bhi(dA) + wB * bhi(dB) + wC * bhi(dC) + wD * bhi(dD);
    }
    for (; j < deg; j++) {
      int sA = __shfl(sreg, j);
      u32 dA = raw2[(size_t)sA * 64 + lane];
      float wA = __shfl(w, j);
      a0 += wA * blo(dA);
      a1 += wA * bhi(dA);
    }
  } else {
    float mx = -1e30f;
    for (int base = beg; base < end; base += 64) {
      int e = base + lane;
      if (e < end) mx = fmaxf(mx, lrelu(as2[srcs[e]] + adv));
    }
    #pragma unroll
    for (int off = 32; off; off >>= 1) mx = fmaxf(mx, __shfl_xor(mx, off));
    for (int base = beg; base < end; base += 64) {
      int cnt = min(64, end - base);
      int sreg = 0;
      float w = 0.f;
      if (lane < cnt) {
        sreg = srcs[base + lane];
        w = __expf(lrelu(as2[sreg] + adv) - mx);
        dsum += w;
      }
      for (int j = 0; j < cnt; j++) {
        int sA = __shfl(sreg, j);
        u32 dA = raw2[(size_t)sA * 64 + lane];
        float wA = __shfl(w, j);
        a0 += wA * blo(dA);
        a1 += wA * bhi(dA);
      }
    }
  }
  #pragma unroll
  for (int off = 32; off; off >>= 1) dsum += __shfl_xor(dsum, off);
  float inv = 1.f / (dsum + 1e-16f);
  float v0 = a0 * inv + bias[2 * lane];
  float v1 = a1 * inv + bias[2 * lane + 1];
  float s1 = v0 + v1, s2 = v0 * v0 + v1 * v1;
  #pragma unroll
  for (int off = 32; off; off >>= 1) {
    s1 += __shfl_xor(s1, off);
    s2 += __shfl_xor(s2, off);
  }
  float mean = s1 * (1.f / 128.f);
  float var = s2 * (1.f / 128.f) - mean * mean;
  float rs = rsqrtf(var + 1e-5f);
  float y0 = fmaxf((v0 - mean) * rs * gam[2 * lane] + bet[2 * lane], 0.f);
  float y1 = fmaxf((v1 - mean) * rs * gam[2 * lane + 1] + bet[2 * lane + 1], 0.f);
  int g = batch[n];
  atomicAdd(&psum[g * 128 + 2 * lane], y0);
  atomicAdd(&psum[g * 128 + 2 * lane + 1], y1);
}

// ---------------- MLP head (counts via binary search on sorted batch) ----------------
__global__ __launch_bounds__(128) void k_head(const float* __restrict__ psum,
    const int* __restrict__ batch, int N,
    const float* __restrict__ rW1, const float* __restrict__ rb1,
    const float* __restrict__ rg, const float* __restrict__ rbe,
    const float* __restrict__ rW2, const float* __restrict__ rb2,
    float* __restrict__ outp) {
  int g = blockIdx.x, t = threadIdx.x;
  __shared__ float pl[128];
  __shared__ float yv[32];
  __shared__ float rv[32];
  __shared__ float mv[2];
  __shared__ int scnt;
  if (t == 0) {
    int lo = 0, hi = N;
    while (lo < hi) { int mid = (lo + hi) >> 1; if (batch[mid] < g) lo = mid + 1; else hi = mid; }
    int lo2 = lo, hi2 = N;
    while (lo2 < hi2) { int mid = (lo2 + hi2) >> 1; if (batch[mid] < g + 1) lo2 = mid + 1; else hi2 = mid; }
    scnt = lo2 - lo;
  }
  __syncthreads();
  float cnt = fmaxf((float)scnt, 1.f);
  pl[t] = psum[g * 128 + t] / cnt;
  __syncthreads();
  if (t < 32) {
    float s = rb1[t];
    for (int c = 0; c < 128; c++) s += pl[c] * rW1[c * 32 + t];
    yv[t] = s;
  }
  __syncthreads();
  if (t == 0) {
    float s = 0.f, sq = 0.f;
    for (int j = 0; j < 32; j++) { s += yv[j]; sq += yv[j] * yv[j]; }
    float mean = s / 32.f;
    float var = sq / 32.f - mean * mean;
    mv[0] = mean; mv[1] = rsqrtf(var + 1e-5f);
  }
  __syncthreads();
  if (t < 32) {
    float y = (yv[t] - mv[0]) * mv[1] * rg[t] + rbe[t];
    rv[t] = fmaxf(y, 0.f);
  }
  __syncthreads();
  if (t < OUT_DIM) {
    float s = rb2[t];
    for (int j = 0; j < 32; j++) s += rv[j] * rW2[j * 8 + t];
    outp[g * 8 + t] = s;
  }
}

extern "C" void kernel_launch(void* const* d_in, const int* in_sizes, int n_in,
                              void* d_out, int out_size, void* d_ws, size_t ws_size,
                              hipStream_t stream) {
  const float* x    = (const float*)d_in[0];
  const int*   ei   = (const int*)d_in[1];
  const int*   batch= (const int*)d_in[3];
  const float* W1   = (const float*)d_in[4];
  const float* as1w = (const float*)d_in[5];
  const float* ad1w = (const float*)d_in[6];
  const float* b1   = (const float*)d_in[7];
  const float* g1   = (const float*)d_in[8];
  const float* be1  = (const float*)d_in[9];
  const float* W2   = (const float*)d_in[10];
  const float* as2w = (const float*)d_in[11];
  const float* ad2w = (const float*)d_in[12];
  const float* b2   = (const float*)d_in[13];
  const float* g2   = (const float*)d_in[14];
  const float* be2  = (const float*)d_in[15];
  const float* rW1  = (const float*)d_in[16];
  const float* rb1  = (const float*)d_in[17];
  const float* rg   = (const float*)d_in[18];
  const float* rbe  = (const float*)d_in[19];
  const float* rW2  = (const float*)d_in[20];
  const float* rb2  = (const float*)d_in[21];

  int N = in_sizes[0] / 128;
  int E = in_sizes[1] / 2;
  int ET = E + N;
  int nb = (N + 255) / 256;

  char* p = (char*)d_ws;
  u16* x_b   = (u16*)p; p += (size_t)N * 128 * 2;
  u16* aggx  = (u16*)p; p += (size_t)N * 512 * 2;
  u16* raw1  = (u16*)p; p += (size_t)N * 512 * 2;
  u16* h1_b  = (u16*)p; p += (size_t)N * 512 * 2;
  u16* raw2b = (u16*)p; p += (size_t)N * 128 * 2;
  u16* W1t   = (u16*)p; p += 512 * 128 * 2;
  u16* W2t   = (u16*)p; p += 128 * 512 * 2;
  float* ws  = (float*)p; p += 128 * 8 * 4;
  float* sa1 = (float*)p; p += (size_t)N * 4 * 4;
  float* da1 = (float*)p; p += (size_t)N * 4 * 4;
  float* sa2 = (float*)p; p += (size_t)N * 4;
  float* da2 = (float*)p; p += (size_t)N * 4;
  float* psum = (float*)p; p += GRAPHS * CH * 4;
  int* counts = (int*)p; p += (size_t)N * 4;
  int* indptr = (int*)p; p += (size_t)(N + 1) * 4;
  int* cursor = (int*)p; p += (size_t)N * 4;
  int* bsum   = (int*)p; p += (size_t)nb * 4;
  int* boff   = (int*)p; p += (size_t)nb * 4;
  int* srcs   = (int*)p; p += (size_t)ET * 4;

  hipMemsetAsync(counts, 0, (size_t)N * sizeof(int), stream);
  hipMemsetAsync(psum, 0, (size_t)GRAPHS * CH * sizeof(float), stream);

  int eb = (ET + 255) / 256;
  k_count<<<eb, 256, 0, stream>>>(ei, counts, E, N);
  k_scanA<<<nb, 256, 0, stream>>>(counts, bsum, N);
  k_scanB<<<1, 1024, 0, stream>>>(bsum, boff, nb);
  k_scanC<<<nb, 256, 0, stream>>>(counts, boff, indptr, cursor, N);
  k_scatter<<<eb, 256, 0, stream>>>(ei, cursor, srcs, E, N);

  // conversions + score matrices
  k_f2b<<<(N * 64 + 255) / 256, 256, 0, stream>>>(x, (u32*)x_b, N * 64);
  k_wt<<<(512 * 128 + 255) / 256, 256, 0, stream>>>(W1, W1t, 128, 512);
  k_wt<<<(512 * 128 + 255) / 256, 256, 0, stream>>>(W2, W2t, 512, 128);
  k_ws<<<1, 256, 0, stream>>>(W1, as1w, ad1w, ws);
  k_score1<<<(N + 3) / 4, 256, 0, stream>>>(x, ws, sa1, da1, N);

  // conv1: aggregate x (wave per node), per-head GEMM (+bias), LN+ReLU
  k_aggx<<<(N + 3) / 4, 256, 0, stream>>>((const u32*)x_b, indptr, srcs,
                                          (const float4*)sa1, (const float4*)da1,
                                          (u32*)aggx, N);
  dim3 gridh((N + 127) / 128, 4);
  k_gemm_head<<<gridh, 256, 0, stream>>>(aggx, W1t, b1, raw1, N);
  k_ln512<<<(N + 3) / 4, 256, 0, stream>>>(raw1, g1, be1, h1_b, N);

  // conv2
  dim3 grid2((N + 127) / 128, 1);
  k_gemm_bf16<<<grid2, 256, 0, stream>>>(h1_b, W2t, raw2b, N, 128, 512);
  k_att_h1<<<(N + 3) / 4, 256, 0, stream>>>(raw2b, as2w, ad2w, sa2, da2, N);
  k_agg2f<<<(N + 3) / 4, 256, 0, stream>>>((const u32*)raw2b, indptr, srcs, sa2, da2,
                                           b2, g2, be2, batch, psum, N);

  // head (counts via binary search, no k_cnt)
  k_head<<<GRAPHS, 128, 0, stream>>>(psum, batch, N, rW1, rb1, rg, rbe, rW2, rb2,
                                     (float*)d_out);
}

// Round 6
// 433.126 us; speedup vs baseline: 2.2023x; 1.0359x over previous
//
#include <hip/hip_runtime.h>
#include <math.h>

#define HEADS 4
#define CH 128
#define HC 512
#define GRAPHS 128
#define OUT_DIM 8

typedef unsigned short u16;
typedef unsigned int u32;
typedef short short8 __attribute__((ext_vector_type(8)));
typedef float f32x4 __attribute__((ext_vector_type(4)));

__device__ inline u16 f2b(float f) {
  u32 u = __float_as_uint(f);
  u32 r = u + 0x7FFFu + ((u >> 16) & 1u);
  return (u16)(r >> 16);
}
__device__ inline float blo(u32 d) { return __uint_as_float(d << 16); }
__device__ inline float bhi(u32 d) { return __uint_as_float(d & 0xffff0000u); }
__device__ inline float lrelu(float v) { return v > 0.f ? v : 0.2f * v; }

// ---------------- CSR build ----------------
__global__ void k_count(const int* __restrict__ ei, int* __restrict__ counts, int E, int N) {
  int i = blockIdx.x * blockDim.x + threadIdx.x;
  int total = E + N;
  if (i >= total) return;
  int dst = (i < E) ? ei[E + i] : (i - E);
  atomicAdd(&counts[dst], 1);
}

__global__ __launch_bounds__(256) void k_scanA(const int* __restrict__ counts,
                                               int* __restrict__ bsum, int N) {
  __shared__ int sh[256];
  int b = blockIdx.x, t = threadIdx.x, i = b * 256 + t;
  sh[t] = (i < N) ? counts[i] : 0;
  __syncthreads();
  for (int off = 128; off; off >>= 1) {
    if (t < off) sh[t] += sh[t + off];
    __syncthreads();
  }
  if (t == 0) bsum[b] = sh[0];
}

__global__ __launch_bounds__(1024) void k_scanB(const int* __restrict__ bsum,
                                                int* __restrict__ boff, int nb) {
  __shared__ int sh[1024];
  int t = threadIdx.x;
  sh[t] = (t < nb) ? bsum[t] : 0;
  __syncthreads();
  for (int off = 1; off < 1024; off <<= 1) {
    int v = sh[t];
    int u = (t >= off) ? sh[t - off] : 0;
    __syncthreads();
    sh[t] = v + u;
    __syncthreads();
  }
  if (t < nb) boff[t] = (t == 0) ? 0 : sh[t - 1];
}

__global__ __launch_bounds__(256) void k_scanC(const int* __restrict__ counts,
                                               const int* __restrict__ boff,
                                               int* __restrict__ indptr,
                                               int* __restrict__ cursor, int N) {
  __shared__ int sh[256];
  int b = blockIdx.x, t = threadIdx.x, i = b * 256 + t;
  int v = (i < N) ? counts[i] : 0;
  sh[t] = v;
  __syncthreads();
  for (int off = 1; off < 256; off <<= 1) {
    int a = sh[t];
    int u = (t >= off) ? sh[t - off] : 0;
    __syncthreads();
    sh[t] = a + u;
    __syncthreads();
  }
  if (i < N) {
    int excl = boff[b] + sh[t] - v;
    indptr[i] = excl;
    cursor[i] = excl;
    if (i == N - 1) indptr[N] = excl + v;
  }
}

__global__ void k_scatter(const int* __restrict__ ei, int* __restrict__ cursor,
                          int* __restrict__ srcs, int E, int N) {
  int i = blockIdx.x * blockDim.x + threadIdx.x;
  int total = E + N;
  if (i >= total) return;
  int src, dst;
  if (i < E) { src = ei[i]; dst = ei[E + i]; } else { src = i - E; dst = i - E; }
  int pos = atomicAdd(&cursor[dst], 1);
  srcs[pos] = src;
}

// ---------------- converters ----------------
__global__ void k_f2b(const float* __restrict__ in, u32* __restrict__ out, int n2) {
  int i = blockIdx.x * blockDim.x + threadIdx.x;
  if (i >= n2) return;
  float2 v = ((const float2*)in)[i];
  out[i] = (u32)f2b(v.x) | ((u32)f2b(v.y) << 16);
}

// W [K][Nc] fp32 -> Wt [Nc][K] bf16 (transposed)
__global__ void k_wt(const float* __restrict__ W, u16* __restrict__ Wt, int K, int Nc) {
  int i = blockIdx.x * blockDim.x + threadIdx.x;
  if (i >= K * Nc) return;
  int n = i / K, k = i - n * K;
  Wt[i] = f2b(W[(size_t)k * Nc + n]);
}

// ws[k][o]: o in 0..3 = src heads, 4..7 = dst heads.  ws = W1_head @ att_head
__global__ __launch_bounds__(256) void k_ws(const float* __restrict__ W1,
                                            const float* __restrict__ as1,
                                            const float* __restrict__ ad1,
                                            float* __restrict__ ws) {
  int t = threadIdx.x;
  #pragma unroll
  for (int r = 0; r < 4; r++) {
    int idx = r * 256 + t;       // 0..1023
    int k = idx >> 3, o = idx & 7, h = o & 3;
    const float* av = ((o < 4) ? as1 : ad1) + h * CH;
    const float* wrow = W1 + (size_t)k * HC + h * CH;
    float s = 0.f;
    for (int c = 0; c < CH; c++) s += wrow[c] * av[c];
    ws[idx] = s;
  }
}

// scores from fp32 x: one wave per node, 8 dots of length 128
__global__ void k_score1(const float* __restrict__ x, const float* __restrict__ ws,
                         float* __restrict__ sa1, float* __restrict__ da1, int N) {
  int n = blockIdx.x * (blockDim.x >> 6) + (threadIdx.x >> 6);
  int lane = threadIdx.x & 63;
  if (n >= N) return;
  const float* row = x + (size_t)n * 128;
  float x0 = row[lane], x1 = row[64 + lane];
  float p[8];
  #pragma unroll
  for (int o = 0; o < 8; o++)
    p[o] = x0 * ws[lane * 8 + o] + x1 * ws[(64 + lane) * 8 + o];
  #pragma unroll
  for (int off = 32; off; off >>= 1)
    #pragma unroll
    for (int o = 0; o < 8; o++) p[o] += __shfl_xor(p[o], off);
  if (lane == 0) {
    #pragma unroll
    for (int h = 0; h < 4; h++) {
      sa1[n * 4 + h] = p[h];
      da1[n * 4 + h] = p[4 + h];
    }
  }
}

// ---------------- conv1 aggregation over x (bf16), 4 heads, WAVE PER NODE ----------------
// Softmax without max-subtraction (shift-invariant; scores are O(1) here).
__global__ __launch_bounds__(256) void k_aggx(
    const u32* __restrict__ xb, const int* __restrict__ indptr,
    const int* __restrict__ srcs, const float4* __restrict__ as1,
    const float4* __restrict__ ad1, u32* __restrict__ aggx, int N) {
  int n = blockIdx.x * 4 + (threadIdx.x >> 6);
  if (n >= N) return;
  int lane = threadIdx.x & 63;
  int beg = indptr[n], end = indptr[n + 1];
  float4 ad = ad1[n];
  float ds0 = 0.f, ds1 = 0.f, ds2 = 0.f, ds3 = 0.f;
  float a00 = 0.f, a01 = 0.f, a10 = 0.f, a11 = 0.f;
  float a20 = 0.f, a21 = 0.f, a30 = 0.f, a31 = 0.f;

  for (int base = beg; base < end; base += 64) {
    int cnt = min(64, end - base);
    int sreg = 0;
    float w0 = 0.f, w1 = 0.f, w2 = 0.f, w3 = 0.f;
    if (lane < cnt) {
      sreg = srcs[base + lane];
      float4 a = as1[sreg];
      w0 = __expf(lrelu(a.x + ad.x));
      w1 = __expf(lrelu(a.y + ad.y));
      w2 = __expf(lrelu(a.z + ad.z));
      w3 = __expf(lrelu(a.w + ad.w));
      ds0 += w0; ds1 += w1; ds2 += w2; ds3 += w3;
    }
    int j = 0;
    for (; j + 4 <= cnt; j += 4) {
      int sA = __shfl(sreg, j), sB = __shfl(sreg, j + 1);
      int sC = __shfl(sreg, j + 2), sD = __shfl(sreg, j + 3);
      u32 dA = xb[(size_t)sA * 64 + lane];
      u32 dB = xb[(size_t)sB * 64 + lane];
      u32 dC = xb[(size_t)sC * 64 + lane];
      u32 dD = xb[(size_t)sD * 64 + lane];
      float xA0 = blo(dA), xA1 = bhi(dA), xB0 = blo(dB), xB1 = bhi(dB);
      float xC0 = blo(dC), xC1 = bhi(dC), xD0 = blo(dD), xD1 = bhi(dD);
      float wA, wB, wC, wD;
      wA = __shfl(w0, j); wB = __shfl(w0, j + 1); wC = __shfl(w0, j + 2); wD = __shfl(w0, j + 3);
      a00 += wA * xA0 + wB * xB0 + wC * xC0 + wD * xD0;
      a01 += wA * xA1 + wB * xB1 + wC * xC1 + wD * xD1;
      wA = __shfl(w1, j); wB = __shfl(w1, j + 1); wC = __shfl(w1, j + 2); wD = __shfl(w1, j + 3);
      a10 += wA * xA0 + wB * xB0 + wC * xC0 + wD * xD0;
      a11 += wA * xA1 + wB * xB1 + wC * xC1 + wD * xD1;
      wA = __shfl(w2, j); wB = __shfl(w2, j + 1); wC = __shfl(w2, j + 2); wD = __shfl(w2, j + 3);
      a20 += wA * xA0 + wB * xB0 + wC * xC0 + wD * xD0;
      a21 += wA * xA1 + wB * xB1 + wC * xC1 + wD * xD1;
      wA = __shfl(w3, j); wB = __shfl(w3, j + 1); wC = __shfl(w3, j + 2); wD = __shfl(w3, j + 3);
      a30 += wA * xA0 + wB * xB0 + wC * xC0 + wD * xD0;
      a31 += wA * xA1 + wB * xB1 + wC * xC1 + wD * xD1;
    }
    for (; j < cnt; j++) {
      int sA = __shfl(sreg, j);
      u32 dA = xb[(size_t)sA * 64 + lane];
      float xA0 = blo(dA), xA1 = bhi(dA);
      float w0A = __shfl(w0, j), w1A = __shfl(w1, j);
      float w2A = __shfl(w2, j), w3A = __shfl(w3, j);
      a00 += w0A * xA0; a01 += w0A * xA1;
      a10 += w1A * xA0; a11 += w1A * xA1;
      a20 += w2A * xA0; a21 += w2A * xA1;
      a30 += w3A * xA0; a31 += w3A * xA1;
    }
  }
  #pragma unroll
  for (int off = 32; off; off >>= 1) {
    ds0 += __shfl_xor(ds0, off);
    ds1 += __shfl_xor(ds1, off);
    ds2 += __shfl_xor(ds2, off);
    ds3 += __shfl_xor(ds3, off);
  }
  float i0 = 1.f / (ds0 + 1e-16f), i1 = 1.f / (ds1 + 1e-16f);
  float i2 = 1.f / (ds2 + 1e-16f), i3 = 1.f / (ds3 + 1e-16f);
  u32* orow = aggx + (size_t)n * 256;
  orow[lane]       = (u32)f2b(a00 * i0) | ((u32)f2b(a01 * i0) << 16);
  orow[64 + lane]  = (u32)f2b(a10 * i1) | ((u32)f2b(a11 * i1) << 16);
  orow[128 + lane] = (u32)f2b(a20 * i2) | ((u32)f2b(a21 * i2) << 16);
  orow[192 + lane] = (u32)f2b(a30 * i3) | ((u32)f2b(a31 * i3) << 16);
}

// ---------------- per-head GEMM: raw1[:, hC:(h+1)C] = aggx[:,h,:] @ W1[:,hC:(h+1)C] + b1 ----------------
__global__ __launch_bounds__(256) void k_gemm_head(
    const u16* __restrict__ A,    // aggx [M][512]
    const u16* __restrict__ Bt,   // W1t  [512][128]
    const float* __restrict__ bias,
    u16* __restrict__ C,          // raw1 [M][512]
    int M) {
  __shared__ u16 As[128 * 64];
  __shared__ u16 Bs[128 * 64];
  int t = threadIdx.x;
  int lane = t & 63, wid = t >> 6;
  int wr = wid >> 1, wc = wid & 1;
  int r0 = blockIdx.x * 128;
  int hh = blockIdx.y;
  const u16* Ah = A + hh * 128;
  const u16* Bh = Bt + (size_t)hh * 128 * 128;
  int lr = lane & 15, lk = lane >> 4;
  f32x4 acc[4][4] = {};
  for (int kt = 0; kt < 128; kt += 64) {
    #pragma unroll
    for (int it = 0; it < 4; it++) {
      int q = wid * 4096 + it * 1024 + lane * 16;
      int row = q >> 7;
      int soff = ((q >> 4) & 7) ^ (row & 7);
      {
        int gr = r0 + row; if (gr >= M) gr = M - 1;
        const u16* gp = Ah + (size_t)gr * 512 + kt + soff * 8;
        __builtin_amdgcn_global_load_lds(
            (const __attribute__((address_space(1))) void*)gp,
            (__attribute__((address_space(3))) void*)((char*)As + wid * 4096 + it * 1024),
            16, 0, 0);
      }
      {
        const u16* gp = Bh + (size_t)row * 128 + kt + soff * 8;
        __builtin_amdgcn_global_load_lds(
            (const __attribute__((address_space(1))) void*)gp,
            (__attribute__((address_space(3))) void*)((char*)Bs + wid * 4096 + it * 1024),
            16, 0, 0);
      }
    }
    __syncthreads();
    const char* Ab = (const char*)As;
    const char* Bb = (const char*)Bs;
    #pragma unroll
    for (int kk = 0; kk < 2; kk++) {
      short8 a[4], b[4];
      #pragma unroll
      for (int m = 0; m < 4; m++) {
        int row = wr * 64 + m * 16 + lr;
        int off = (row << 7) + kk * 64 + lk * 16;
        off ^= (row & 7) << 4;
        a[m] = *(const short8*)(Ab + off);
      }
      #pragma unroll
      for (int nn = 0; nn < 4; nn++) {
        int row = wc * 64 + nn * 16 + lr;
        int off = (row << 7) + kk * 64 + lk * 16;
        off ^= (row & 7) << 4;
        b[nn] = *(const short8*)(Bb + off);
      }
      #pragma unroll
      for (int m = 0; m < 4; m++)
        #pragma unroll
        for (int nn = 0; nn < 4; nn++)
          acc[m][nn] = __builtin_amdgcn_mfma_f32_16x16x32_bf16(a[m], b[nn], acc[m][nn], 0, 0, 0);
    }
    __syncthreads();
  }
  #pragma unroll
  for (int m = 0; m < 4; m++)
    #pragma unroll
    for (int nn = 0; nn < 4; nn++)
      #pragma unroll
      for (int r = 0; r < 4; r++) {
        int row = r0 + wr * 64 + m * 16 + lk * 4 + r;
        if (row < M) {
          int gcol = hh * 128 + wc * 64 + nn * 16 + lr;
          C[(size_t)row * 512 + gcol] = f2b(acc[m][nn][r] + bias[gcol]);
        }
      }
}

// ---------------- LN+ReLU over 512 channels (bf16 in/out) ----------------
__global__ __launch_bounds__(256) void k_ln512(const u16* __restrict__ raw,
                                               const float* __restrict__ gam,
                                               const float* __restrict__ bet,
                                               u16* __restrict__ out, int N) {
  int n = blockIdx.x * 4 + (threadIdx.x >> 6);
  int lane = threadIdx.x & 63;
  if (n >= N) return;
  const uint4* r = (const uint4*)(raw + (size_t)n * 512);
  uint4 q = r[lane];
  float v[8];
  v[0] = blo(q.x); v[1] = bhi(q.x); v[2] = blo(q.y); v[3] = bhi(q.y);
  v[4] = blo(q.z); v[5] = bhi(q.z); v[6] = blo(q.w); v[7] = bhi(q.w);
  float s1 = 0.f, s2 = 0.f;
  #pragma unroll
  for (int j = 0; j < 8; j++) { s1 += v[j]; s2 += v[j] * v[j]; }
  #pragma unroll
  for (int off = 32; off; off >>= 1) {
    s1 += __shfl_xor(s1, off);
    s2 += __shfl_xor(s2, off);
  }
  float mean = s1 * (1.f / 512.f);
  float var = s2 * (1.f / 512.f) - mean * mean;
  float rs = rsqrtf(var + 1e-5f);
  u32 o[4];
  #pragma unroll
  for (int j = 0; j < 4; j++) {
    int ch = lane * 8 + 2 * j;
    float y0 = fmaxf((v[2 * j] - mean) * rs * gam[ch] + bet[ch], 0.f);
    float y1 = fmaxf((v[2 * j + 1] - mean) * rs * gam[ch + 1] + bet[ch + 1], 0.f);
    o[j] = (u32)f2b(y0) | ((u32)f2b(y1) << 16);
  }
  ((uint4*)(out + (size_t)n * 512))[lane] = make_uint4(o[0], o[1], o[2], o[3]);
}

// ---------------- bf16 MFMA GEMM (conv2): C[M][128] = A[M][512] * Bt[128][512]^T ----------------
__global__ __launch_bounds__(256) void k_gemm_bf16(
    const u16* __restrict__ A, const u16* __restrict__ Bt,
    u16* __restrict__ C, int M, int Nc, int K) {
  __shared__ u16 As[128 * 64];
  __shared__ u16 Bs[128 * 64];
  int t = threadIdx.x;
  int lane = t & 63, wid = t >> 6;
  int wr = wid >> 1, wc = wid & 1;
  int r0 = blockIdx.x * 128, c0 = blockIdx.y * 128;
  int lr = lane & 15, lk = lane >> 4;
  f32x4 acc[4][4] = {};
  for (int kt = 0; kt < K; kt += 64) {
    #pragma unroll
    for (int it = 0; it < 4; it++) {
      int q = wid * 4096 + it * 1024 + lane * 16;
      int row = q >> 7;
      int soff = ((q >> 4) & 7) ^ (row & 7);
      {
        int gr = r0 + row; if (gr >= M) gr = M - 1;
        const u16* gp = A + (size_t)gr * K + kt + soff * 8;
        __builtin_amdgcn_global_load_lds(
            (const __attribute__((address_space(1))) void*)gp,
            (__attribute__((address_space(3))) void*)((char*)As + wid * 4096 + it * 1024),
            16, 0, 0);
      }
      {
        int gn = c0 + row;
        const u16* gp = Bt + (size_t)gn * K + kt + soff * 8;
        __builtin_amdgcn_global_load_lds(
            (const __attribute__((address_space(1))) void*)gp,
            (__attribute__((address_space(3))) void*)((char*)Bs + wid * 4096 + it * 1024),
            16, 0, 0);
      }
    }
    __syncthreads();
    const char* Ab = (const char*)As;
    const char* Bb = (const char*)Bs;
    #pragma unroll
    for (int kk = 0; kk < 2; kk++) {
      short8 a[4], b[4];
      #pragma unroll
      for (int m = 0; m < 4; m++) {
        int row = wr * 64 + m * 16 + lr;
        int off = (row << 7) + kk * 64 + lk * 16;
        off ^= (row & 7) << 4;
        a[m] = *(const short8*)(Ab + off);
      }
      #pragma unroll
      for (int nn = 0; nn < 4; nn++) {
        int row = wc * 64 + nn * 16 + lr;
        int off = (row << 7) + kk * 64 + lk * 16;
        off ^= (row & 7) << 4;
        b[nn] = *(const short8*)(Bb + off);
      }
      #pragma unroll
      for (int m = 0; m < 4; m++)
        #pragma unroll
        for (int nn = 0; nn < 4; nn++)
          acc[m][nn] = __builtin_amdgcn_mfma_f32_16x16x32_bf16(a[m], b[nn], acc[m][nn], 0, 0, 0);
    }
    __syncthreads();
  }
  #pragma unroll
  for (int m = 0; m < 4; m++)
    #pragma unroll
    for (int nn = 0; nn < 4; nn++)
      #pragma unroll
      for (int r = 0; r < 4; r++) {
        int row = r0 + wr * 64 + m * 16 + lk * 4 + r;
        if (row < M) {
          int col = c0 + wc * 64 + nn * 16 + lr;
          C[(size_t)row * Nc + col] = f2b(acc[m][nn][r]);
        }
      }
}

// ---------------- conv2 scores ----------------
__global__ void k_att_h1(const u16* __restrict__ hm, const float* __restrict__ att_s,
                         const float* __restrict__ att_d, float* __restrict__ s_out,
                         float* __restrict__ d_out, int N) {
  int n = blockIdx.x * (blockDim.x >> 6) + (threadIdx.x >> 6);
  int lane = threadIdx.x & 63;
  if (n >= N) return;
  const u32* row = (const u32*)(hm + (size_t)n * CH);
  u32 d = row[lane];
  float x0 = blo(d), x1 = bhi(d);
  float ps = x0 * att_s[2 * lane] + x1 * att_s[2 * lane + 1];
  float pd = x0 * att_d[2 * lane] + x1 * att_d[2 * lane + 1];
  #pragma unroll
  for (int off = 32; off; off >>= 1) {
    ps += __shfl_xor(ps, off);
    pd += __shfl_xor(pd, off);
  }
  if (lane == 0) { s_out[n] = ps; d_out[n] = pd; }
}

// ---------------- conv2 aggregation + bias + LN + ReLU + pool, WAVE PER NODE ----------------
// Softmax without max-subtraction; 8 row-loads in flight.
__global__ __launch_bounds__(256) void k_agg2f(
    const u32* __restrict__ raw2, const int* __restrict__ indptr,
    const int* __restrict__ srcs, const float* __restrict__ as2,
    const float* __restrict__ ad2, const float* __restrict__ bias,
    const float* __restrict__ gam, const float* __restrict__ bet,
    const int* __restrict__ batch, float* __restrict__ psum, int N) {
  int n = blockIdx.x * 4 + (threadIdx.x >> 6);
  if (n >= N) return;
  int lane = threadIdx.x & 63;
  int beg = indptr[n], end = indptr[n + 1];
  float adv = ad2[n];
  float dsum = 0.f, a0 = 0.f, a1 = 0.f;

  for (int base = beg; base < end; base += 64) {
    int cnt = min(64, end - base);
    int sreg = 0;
    float w = 0.f;
    if (lane < cnt) {
      sreg = srcs[base + lane];
      w = __expf(lrelu(as2[sreg] + adv));
      dsum += w;
    }
    int j = 0;
    for (; j + 8 <= cnt; j += 8) {
      int s0 = __shfl(sreg, j),     s1 = __shfl(sreg, j + 1);
      int s2 = __shfl(sreg, j + 2), s3 = __shfl(sreg, j + 3);
      int s4 = __shfl(sreg, j + 4), s5 = __shfl(sreg, j + 5);
      int s6 = __shfl(sreg, j + 6), s7 = __shfl(sreg, j + 7);
      u32 d0 = raw2[(size_t)s0 * 64 + lane];
      u32 d1 = raw2[(size_t)s1 * 64 + lane];
      u32 d2 = raw2[(size_t)s2 * 64 + lane];
      u32 d3 = raw2[(size_t)s3 * 64 + lane];
      u32 d4 = raw2[(size_t)s4 * 64 + lane];
      u32 d5 = raw2[(size_t)s5 * 64 + lane];
      u32 d6 = raw2[(size_t)s6 * 64 + lane];
      u32 d7 = raw2[(size_t)s7 * 64 + lane];
      float w0 = __shfl(w, j),     w1 = __shfl(w, j + 1);
      float w2 = __shfl(w, j + 2), w3 = __shfl(w, j + 3);
      float w4 = __shfl(w, j + 4), w5 = __shfl(w, j + 5);
      float w6 = __shfl(w, j + 6), w7 = __shfl(w, j + 7);
      a0 += w0 * blo(d0) + w1 * blo(d1) + w2 * blo(d2) + w3 * blo(d3)
          + w4 * blo(d4) + w5 * blo(d5) + w6 * blo(d6) + w7 * blo(d7);
      a1 += w0 * bhi(d0) + w1 * bhi(d1) + w2 * bhi(d2) + w3 * bhi(d3)
          + w4 * bhi(d4) + w5 * bhi(d5) + w6 * bhi(d6) + w7 * bhi(d7);
    }
    for (; j < cnt; j++) {
      int sA = __shfl(sreg, j);
      u32 dA = raw2[(size_t)sA * 64 + lane];
      float wA = __shfl(w, j);
      a0 += wA * blo(dA);
      a1 += wA * bhi(dA);
    }
  }
  #pragma unroll
  for (int off = 32; off; off >>= 1) dsum += __shfl_xor(dsum, off);
  float inv = 1.f / (dsum + 1e-16f);
  float v0 = a0 * inv + bias[2 * lane];
  float v1 = a1 * inv + bias[2 * lane + 1];
  float s1 = v0 + v1, s2 = v0 * v0 + v1 * v1;
  #pragma unroll
  for (int off = 32; off; off >>= 1) {
    s1 += __shfl_xor(s1, off);
    s2 += __shfl_xor(s2, off);
  }
  float mean = s1 * (1.f / 128.f);
  float var = s2 * (1.f / 128.f) - mean * mean;
  float rs = rsqrtf(var + 1e-5f);
  float y0 = fmaxf((v0 - mean) * rs * gam[2 * lane] + bet[2 * lane], 0.f);
  float y1 = fmaxf((v1 - mean) * rs * gam[2 * lane + 1] + bet[2 * lane + 1], 0.f);
  int g = batch[n];
  atomicAdd(&psum[g * 128 + 2 * lane], y0);
  atomicAdd(&psum[g * 128 + 2 * lane + 1], y1);
}

// ---------------- MLP head (counts via binary search on sorted batch) ----------------
__global__ __launch_bounds__(128) void k_head(const float* __restrict__ psum,
    const int* __restrict__ batch, int N,
    const float* __restrict__ rW1, const float* __restrict__ rb1,
    const float* __restrict__ rg, const float* __restrict__ rbe,
    const float* __restrict__ rW2, const float* __restrict__ rb2,
    float* __restrict__ outp) {
  int g = blockIdx.x, t = threadIdx.x;
  __shared__ float pl[128];
  __shared__ float yv[32];
  __shared__ float rv[32];
  __shared__ float mv[2];
  __shared__ int scnt;
  if (t == 0) {
    int lo = 0, hi = N;
    while (lo < hi) { int mid = (lo + hi) >> 1; if (batch[mid] < g) lo = mid + 1; else hi = mid; }
    int lo2 = lo, hi2 = N;
    while (lo2 < hi2) { int mid = (lo2 + hi2) >> 1; if (batch[mid] < g + 1) lo2 = mid + 1; else hi2 = mid; }
    scnt = lo2 - lo;
  }
  __syncthreads();
  float cnt = fmaxf((float)scnt, 1.f);
  pl[t] = psum[g * 128 + t] / cnt;
  __syncthreads();
  if (t < 32) {
    float s = rb1[t];
    for (int c = 0; c < 128; c++) s += pl[c] * rW1[c * 32 + t];
    yv[t] = s;
  }
  __syncthreads();
  if (t == 0) {
    float s = 0.f, sq = 0.f;
    for (int j = 0; j < 32; j++) { s += yv[j]; sq += yv[j] * yv[j]; }
    float mean = s / 32.f;
    float var = sq / 32.f - mean * mean;
    mv[0] = mean; mv[1] = rsqrtf(var + 1e-5f);
  }
  __syncthreads();
  if (t < 32) {
    float y = (yv[t] - mv[0]) * mv[1] * rg[t] + rbe[t];
    rv[t] = fmaxf(y, 0.f);
  }
  __syncthreads();
  if (t < OUT_DIM) {
    float s = rb2[t];
    for (int j = 0; j < 32; j++) s += rv[j] * rW2[j * 8 + t];
    outp[g * 8 + t] = s;
  }
}

extern "C" void kernel_launch(void* const* d_in, const int* in_sizes, int n_in,
                              void* d_out, int out_size, void* d_ws, size_t ws_size,
                              hipStream_t stream) {
  const float* x    = (const float*)d_in[0];
  const int*   ei   = (const int*)d_in[1];
  const int*   batch= (const int*)d_in[3];
  const float* W1   = (const float*)d_in[4];
  const float* as1w = (const float*)d_in[5];
  const float* ad1w = (const float*)d_in[6];
  const float* b1   = (const float*)d_in[7];
  const float* g1   = (const float*)d_in[8];
  const float* be1  = (const float*)d_in[9];
  const float* W2   = (const float*)d_in[10];
  const float* as2w = (const float*)d_in[11];
  const float* ad2w = (const float*)d_in[12];
  const float* b2   = (const float*)d_in[13];
  const float* g2   = (const float*)d_in[14];
  const float* be2  = (const float*)d_in[15];
  const float* rW1  = (const float*)d_in[16];
  const float* rb1  = (const float*)d_in[17];
  const float* rg   = (const float*)d_in[18];
  const float* rbe  = (const float*)d_in[19];
  const float* rW2  = (const float*)d_in[20];
  const float* rb2  = (const float*)d_in[21];

  int N = in_sizes[0] / 128;
  int E = in_sizes[1] / 2;
  int ET = E + N;
  int nb = (N + 255) / 256;

  char* p = (char*)d_ws;
  u16* x_b   = (u16*)p; p += (size_t)N * 128 * 2;
  u16* aggx  = (u16*)p; p += (size_t)N * 512 * 2;
  u16* raw1  = (u16*)p; p += (size_t)N * 512 * 2;
  u16* h1_b  = (u16*)p; p += (size_t)N * 512 * 2;
  u16* raw2b = (u16*)p; p += (size_t)N * 128 * 2;
  u16* W1t   = (u16*)p; p += 512 * 128 * 2;
  u16* W2t   = (u16*)p; p += 128 * 512 * 2;
  float* ws  = (float*)p; p += 128 * 8 * 4;
  float* sa1 = (float*)p; p += (size_t)N * 4 * 4;
  float* da1 = (float*)p; p += (size_t)N * 4 * 4;
  float* sa2 = (float*)p; p += (size_t)N * 4;
  float* da2 = (float*)p; p += (size_t)N * 4;
  float* psum = (float*)p; p += GRAPHS * CH * 4;
  int* counts = (int*)p; p += (size_t)N * 4;
  int* indptr = (int*)p; p += (size_t)(N + 1) * 4;
  int* cursor = (int*)p; p += (size_t)N * 4;
  int* bsum   = (int*)p; p += (size_t)nb * 4;
  int* boff   = (int*)p; p += (size_t)nb * 4;
  int* srcs   = (int*)p; p += (size_t)ET * 4;

  hipMemsetAsync(counts, 0, (size_t)N * sizeof(int), stream);
  hipMemsetAsync(psum, 0, (size_t)GRAPHS * CH * sizeof(float), stream);

  int eb = (ET + 255) / 256;
  k_count<<<eb, 256, 0, stream>>>(ei, counts, E, N);
  k_scanA<<<nb, 256, 0, stream>>>(counts, bsum, N);
  k_scanB<<<1, 1024, 0, stream>>>(bsum, boff, nb);
  k_scanC<<<nb, 256, 0, stream>>>(counts, boff, indptr, cursor, N);
  k_scatter<<<eb, 256, 0, stream>>>(ei, cursor, srcs, E, N);

  // conversions + score matrices
  k_f2b<<<(N * 64 + 255) / 256, 256, 0, stream>>>(x, (u32*)x_b, N * 64);
  k_wt<<<(512 * 128 + 255) / 256, 256, 0, stream>>>(W1, W1t, 128, 512);
  k_wt<<<(512 * 128 + 255) / 256, 256, 0, stream>>>(W2, W2t, 512, 128);
  k_ws<<<1, 256, 0, stream>>>(W1, as1w, ad1w, ws);
  k_score1<<<(N + 3) / 4, 256, 0, stream>>>(x, ws, sa1, da1, N);

  // conv1: aggregate x (wave per node), per-head GEMM (+bias), LN+ReLU
  k_aggx<<<(N + 3) / 4, 256, 0, stream>>>((const u32*)x_b, indptr, srcs,
                                          (const float4*)sa1, (const float4*)da1,
                                          (u32*)aggx, N);
  dim3 gridh((N + 127) / 128, 4);
  k_gemm_head<<<gridh, 256, 0, stream>>>(aggx, W1t, b1, raw1, N);
  k_ln512<<<(N + 3) / 4, 256, 0, stream>>>(raw1, g1, be1, h1_b, N);

  // conv2
  dim3 grid2((N + 127) / 128, 1);
  k_gemm_bf16<<<grid2, 256, 0, stream>>>(h1_b, W2t, raw2b, N, 128, 512);
  k_att_h1<<<(N + 3) / 4, 256, 0, stream>>>(raw2b, as2w, ad2w, sa2, da2, N);
  k_agg2f<<<(N + 3) / 4, 256, 0, stream>>>((const u32*)raw2b, indptr, srcs, sa2, da2,
                                           b2, g2, be2, batch, psum, N);

  // head (counts via binary search, no k_cnt)
  k_head<<<GRAPHS, 128, 0, stream>>>(psum, batch, N, rW1, rb1, rg, rbe, rW2, rb2,
                                     (float*)d_out);
}